// Round 7
// baseline (2868.306 us; speedup 1.0000x reference)
//
#include <hip/hip_runtime.h>
#include <math.h>

#define NB 8
#define C 256
#define HW 1024
#define NS 64

typedef unsigned short u16;
typedef __attribute__((ext_vector_type(8))) short bf16x8;
typedef __attribute__((ext_vector_type(4))) short bf16x4;
typedef __attribute__((ext_vector_type(4))) float f32x4;

__device__ __forceinline__ u16 f2bf(float x) {
    union { float f; unsigned u; } v; v.f = x;
    unsigned r = v.u + 0x7fffu + ((v.u >> 16) & 1u);
    return (u16)(r >> 16);
}
__device__ __forceinline__ float bf2f(u16 h) {
    union { unsigned u; float f; } v; v.u = ((unsigned)h) << 16; return v.f;
}
__device__ __forceinline__ void splitbf(float x, short& h, short& l) {
    u16 hh = f2bf(x);
    h = (short)hh;
    l = (short)f2bf(x - bf2f(hh));
}

// ---------------- block reduction helpers (256 threads = 4 waves) ----------------
__device__ __forceinline__ float blockReduceSum(float v, float* s4) {
    #pragma unroll
    for (int o = 32; o; o >>= 1) v += __shfl_down(v, o);
    __syncthreads();
    if ((threadIdx.x & 63) == 0) s4[threadIdx.x >> 6] = v;
    __syncthreads();
    return s4[0] + s4[1] + s4[2] + s4[3];
}
__device__ __forceinline__ float blockReduceMax(float v, float* s4) {
    #pragma unroll
    for (int o = 32; o; o >>= 1) v = fmaxf(v, __shfl_down(v, o));
    __syncthreads();
    if ((threadIdx.x & 63) == 0) s4[threadIdx.x >> 6] = v;
    __syncthreads();
    return fmaxf(fmaxf(s4[0], s4[1]), fmaxf(s4[2], s4[3]));
}

// ================= PRODUCTION (r5, verified) =================

__global__ void k_conv_sc(const float* __restrict__ seg,
                          const float* __restrict__ ws1, const float* __restrict__ bs1,
                          const float* __restrict__ ws11, const float* __restrict__ bs11,
                          float* __restrict__ seg_s, float* __restrict__ seg_c) {
    int s = blockIdx.x, n = blockIdx.y, tid = threadIdx.x;
    __shared__ float w1[C], w2[C];
    w1[tid] = ws1[s * C + tid];
    w2[tid] = ws11[s * C + tid];
    __syncthreads();
    const float* sb = seg + (size_t)n * C * HW;
    float a0 = 0, a1 = 0, a2 = 0, a3 = 0, b0 = 0, b1 = 0, b2 = 0, b3 = 0;
    for (int c = 0; c < C; ++c) {
        const float* row = sb + (size_t)c * HW;
        float w1c = w1[c], w2c = w2[c];
        float s0 = row[tid], s1 = row[tid + 256], s2 = row[tid + 512], s3 = row[tid + 768];
        a0 += s0 * w1c; a1 += s1 * w1c; a2 += s2 * w1c; a3 += s3 * w1c;
        b0 += s0 * w2c; b1 += s1 * w2c; b2 += s2 * w2c; b3 += s3 * w2c;
    }
    float bias1 = bs1[s], bias2 = bs11[s];
    float* o1 = seg_s + ((size_t)n * NS + s) * HW;
    float* o2 = seg_c + ((size_t)n * NS + s) * HW;
    o1[tid] = a0 + bias1; o1[tid + 256] = a1 + bias1; o1[tid + 512] = a2 + bias1; o1[tid + 768] = a3 + bias1;
    o2[tid] = b0 + bias2; o2[tid + 256] = b1 + bias2; o2[tid + 512] = b2 + bias2; o2[tid + 768] = b3 + bias2;
}

__global__ void k_pooled(const float* __restrict__ seg, float* __restrict__ pooled) {
    int c = blockIdx.x, n = blockIdx.y, tid = threadIdx.x;
    const float* row = seg + ((size_t)n * C + c) * HW;
    float acc = row[tid] + row[tid + 256] + row[tid + 512] + row[tid + 768];
    __shared__ float s4[4];
    float r = blockReduceSum(acc, s4);
    if (tid == 0) pooled[n * C + c] = r * (1.0f / HW);
}

__global__ void k_ca(const float* __restrict__ pooled, const float* __restrict__ wmlp,
                     const float* __restrict__ bmlp, float* __restrict__ ca) {
    int n = blockIdx.x, s = threadIdx.x;
    __shared__ float pl[C];
    for (int i = s; i < C; i += 64) pl[i] = pooled[n * C + i];
    __syncthreads();
    float acc = 0.f;
    for (int c = 0; c < C; ++c) acc += pl[c] * wmlp[s * C + c];
    float r = acc + bmlp[s];
    ca[n * NS + s] = r > 0.f ? r : 0.f;
}

__global__ void k_vecs(const float* __restrict__ seg, const float* __restrict__ edge,
                       const float* __restrict__ seg_s, const float* __restrict__ ca,
                       const float* __restrict__ ws2, const float* __restrict__ bs2,
                       const float* __restrict__ ws3, const float* __restrict__ bs3,
                       float* __restrict__ u, float* __restrict__ vv,
                       float* __restrict__ segss, float* __restrict__ edgemm) {
    int pos = blockIdx.x * 256 + threadIdx.x;
    int n = blockIdx.y, role = blockIdx.z;
    if (role == 0) {
        __shared__ float cs[NS];
        if (threadIdx.x < NS) cs[threadIdx.x] = ca[n * NS + threadIdx.x];
        __syncthreads();
        const float* base = seg_s + (size_t)n * NS * HW + (size_t)pos * NS;
        float acc = 0.f;
        #pragma unroll
        for (int s = 0; s < NS; ++s) acc += base[s] * cs[s];
        u[n * HW + pos] = acc;
    } else if (role == 1) {
        __shared__ float cs[NS];
        if (threadIdx.x < NS) cs[threadIdx.x] = ca[n * NS + threadIdx.x];
        __syncthreads();
        const float* base = seg_s + (size_t)n * NS * HW + pos;
        float acc = 0.f;
        #pragma unroll
        for (int s = 0; s < NS; ++s) acc += cs[s] * base[(size_t)s * HW];
        vv[n * HW + pos] = acc;
    } else if (role == 2) {
        const float* base = seg + (size_t)n * C * HW + pos;
        float m = -3.402823466e38f;
        for (int c = 0; c < C; ++c) m = fmaxf(m, base[(size_t)c * HW]);
        segss[n * HW + pos] = ws2[0] * m + bs2[0];
    } else {
        const float* sb = seg + (size_t)n * C * HW + pos;
        const float* eb = edge + (size_t)n * C * HW + pos;
        float m = -3.402823466e38f;
        for (int c = 0; c < C; ++c) m = fmaxf(m, sb[(size_t)c * HW] * eb[(size_t)c * HW]);
        edgemm[n * HW + pos] = ws3[0] * m + bs3[0];
    }
}

template <int MODE>
__global__ void k_gemm64(const float* __restrict__ A, long long strideA, int lda,
                         const float* __restrict__ Bm, long long strideB, int ldb,
                         float* __restrict__ Cm, long long strideC, int ldc, int K,
                         const float* __restrict__ e1, long long se1,
                         const float* __restrict__ e2, long long se2) {
    int n = blockIdx.z;
    int m0 = blockIdx.y * 64, q0 = blockIdx.x * 64;
    const float* Ab = A + (size_t)n * strideA;
    const float* Bb = Bm + (size_t)n * strideB;
    float* Cb = Cm + (size_t)n * strideC;
    __shared__ float As[64][33];
    __shared__ float Bs[32][64];
    int tid = threadIdx.x, tx = tid & 15, ty = tid >> 4;
    float acc[4][4] = {};
    for (int k0 = 0; k0 < K; k0 += 32) {
        #pragma unroll
        for (int i = 0; i < 8; ++i) {
            int e = tid + i * 256;
            int ml = e >> 5, kl = e & 31;
            As[ml][kl] = Ab[(size_t)(m0 + ml) * lda + k0 + kl];
        }
        #pragma unroll
        for (int i = 0; i < 8; ++i) {
            int e = tid + i * 256;
            int kl = e >> 6, nl = e & 63;
            Bs[kl][nl] = Bb[(size_t)(k0 + kl) * ldb + q0 + nl];
        }
        __syncthreads();
        #pragma unroll
        for (int kk = 0; kk < 32; ++kk) {
            float a0 = As[ty * 4 + 0][kk], a1 = As[ty * 4 + 1][kk];
            float a2 = As[ty * 4 + 2][kk], a3 = As[ty * 4 + 3][kk];
            float4 b = *(const float4*)&Bs[kk][tx * 4];
            acc[0][0] += a0 * b.x; acc[0][1] += a0 * b.y; acc[0][2] += a0 * b.z; acc[0][3] += a0 * b.w;
            acc[1][0] += a1 * b.x; acc[1][1] += a1 * b.y; acc[1][2] += a1 * b.z; acc[1][3] += a1 * b.w;
            acc[2][0] += a2 * b.x; acc[2][1] += a2 * b.y; acc[2][2] += a2 * b.z; acc[2][3] += a2 * b.w;
            acc[3][0] += a3 * b.x; acc[3][1] += a3 * b.y; acc[3][2] += a3 * b.z; acc[3][3] += a3 * b.w;
        }
        __syncthreads();
    }
    #pragma unroll
    for (int i = 0; i < 4; ++i) {
        int m = m0 + ty * 4 + i;
        float* crow = Cb + (size_t)m * ldc + q0 + tx * 4;
        #pragma unroll
        for (int j = 0; j < 4; ++j) {
            int q = q0 + tx * 4 + j;
            float val = acc[i][j];
            if (MODE == 1) {
                val *= e1[(size_t)n * se1 + m] * e2[(size_t)n * se2 + q];
            } else if (MODE == 2) {
                val = fmaxf(val + e1[m], 0.f) + e2[(size_t)n * se2 + (size_t)m * ldc + q];
            } else if (MODE == 3) {
                val = 0.5f * val + 0.5f * e2[(size_t)n * se2 + (size_t)m * ldc + q];
            }
            crow[j] = val;
        }
    }
}

__global__ void k_symB(float* __restrict__ B) {
    int p = blockIdx.x, n = blockIdx.y;
    float* Bb = B + (size_t)n * HW * HW;
    for (int q = p + threadIdx.x; q < HW; q += 256) {
        float x = Bb[(size_t)p * HW + q];
        float y = Bb[(size_t)q * HW + p];
        x = x < 0.15f ? 0.f : x;
        y = y < 0.15f ? 0.f : y;
        float m = 0.5f * (x + y);
        Bb[(size_t)p * HW + q] = m;
        Bb[(size_t)q * HW + p] = m;
    }
}

__global__ void k_rowsum_cs(const float* __restrict__ B, const float* __restrict__ u,
                            const float* __restrict__ vv, float* __restrict__ dcinv,
                            float* __restrict__ dsinv) {
    int p = blockIdx.x, n = blockIdx.y, tid = threadIdx.x;
    const float* Bb = B + (size_t)n * HW * HW + (size_t)p * HW;
    const float* un = u + n * HW;
    const float* vn = vv + n * HW;
    float up = un[p], vp = vn[p];
    float acc_s = 0.f, acc_c = 0.f;
    for (int q = tid; q < HW; q += 256) {
        acc_s += Bb[q];
        float x = up * vn[q]; x = x < 0.15f ? 0.f : x;
        float y = un[q] * vp; y = y < 0.15f ? 0.f : y;
        acc_c += 0.5f * (x + y);
    }
    __shared__ float s4[4];
    acc_s = blockReduceSum(acc_s, s4);
    acc_c = blockReduceSum(acc_c, s4);
    if (tid == 0) {
        dsinv[n * HW + p] = 1.0f / sqrtf(acc_s + 1.0f);
        dcinv[n * HW + p] = 1.0f / sqrtf(acc_c + 1.0f);
    }
}

__global__ void k_build_sim(float* __restrict__ B, const float* __restrict__ u,
                            const float* __restrict__ vv, const float* __restrict__ dcinv,
                            const float* __restrict__ dsinv, float* __restrict__ dfinv) {
    int p = blockIdx.x, n = blockIdx.y, tid = threadIdx.x;
    float* Bb = B + (size_t)n * HW * HW + (size_t)p * HW;
    const float* un = u + n * HW;
    const float* vn = vv + n * HW;
    const float* dci = dcinv + n * HW;
    const float* dsi = dsinv + n * HW;
    float up = un[p], vp = vn[p], dcp = dci[p], dsp = dsi[p];
    float acc = 0.f;
    for (int q = tid; q < HW; q += 256) {
        float x = up * vn[q]; x = x < 0.15f ? 0.f : x;
        float y = un[q] * vp; y = y < 0.15f ? 0.f : y;
        float delta = (q == p) ? 1.0f : 0.0f;
        float val = (0.5f * (x + y) + delta) * dcp * dci[q] + (Bb[q] + delta) * dsp * dsi[q];
        Bb[q] = val;
        acc += val;
    }
    __shared__ float s4[4];
    acc = blockReduceSum(acc, s4);
    if (tid == 0) dfinv[n * HW + p] = 1.0f / sqrtf(acc + 1.0f);
}

__global__ void k_norm_accum(float* __restrict__ B, const float* __restrict__ dfinv,
                             float* __restrict__ ACC, int first) {
    int p = blockIdx.x, n = blockIdx.y, tid = threadIdx.x;
    float* Bb = B + (size_t)n * HW * HW + (size_t)p * HW;
    float* Ab = ACC + (size_t)n * HW * HW + (size_t)p * HW;
    const float* df = dfinv + n * HW;
    float dfp = df[p];
    for (int q = tid; q < HW; q += 256) {
        float val = (Bb[q] + ((q == p) ? 1.f : 0.f)) * dfp * df[q];
        Bb[q] = val;
        Ab[q] = first ? val : (Ab[q] + val);
    }
}

__global__ void k_final_rowsum(const float* __restrict__ ACC, float* __restrict__ dinv) {
    int p = blockIdx.x, n = blockIdx.y, tid = threadIdx.x;
    const float* Ab = ACC + (size_t)n * HW * HW + (size_t)p * HW;
    float acc = 0.f;
    for (int q = tid; q < HW; q += 256) acc += Ab[q];
    __shared__ float s4[4];
    acc = blockReduceSum(acc, s4);
    if (tid == 0) dinv[n * HW + p] = 1.0f / sqrtf(acc * (1.0f / 3.0f) + 1.0f);
}

__global__ void k_final_norm(float* __restrict__ ACC, const float* __restrict__ dinv,
                             float* __restrict__ rowsf, float* __restrict__ diagrow,
                             float* __restrict__ sqrow) {
    int p = blockIdx.x, n = blockIdx.y, tid = threadIdx.x;
    float* Ab = ACC + (size_t)n * HW * HW + (size_t)p * HW;
    const float* di = dinv + n * HW;
    float dp = di[p];
    float accr = 0.f, accsq = 0.f, accd = 0.f;
    for (int q = tid; q < HW; q += 256) {
        float val = (Ab[q] * (1.0f / 3.0f) + ((q == p) ? 1.f : 0.f)) * dp * di[q];
        Ab[q] = val;
        accr += val;
        accsq += val * val;
        if (q == p) accd = val;
    }
    __shared__ float s4[4];
    accr = blockReduceSum(accr, s4);
    accsq = blockReduceSum(accsq, s4);
    accd = blockReduceSum(accd, s4);
    if (tid == 0) {
        rowsf[n * HW + p] = accr;
        sqrow[n * HW + p] = accsq;
        diagrow[n * HW + p] = accd;
    }
}

__global__ void k_scal(const float* __restrict__ diagrow, const float* __restrict__ sqrow,
                       float* __restrict__ scal) {
    int tid = threadIdx.x;
    float a = 0.f, b = 0.f;
    for (int i = tid; i < NB * HW; i += 256) { a += diagrow[i]; b += sqrow[i]; }
    __shared__ float s4[4];
    a = blockReduceSum(a, s4);
    b = blockReduceSum(b, s4);
    if (tid == 0) { scal[0] = a; scal[1] = b; }
}

__global__ void k_reg(const float* __restrict__ rowsf, const float* __restrict__ scal,
                      float* __restrict__ outreg) {
    int n = blockIdx.x, tid = threadIdx.x;
    float acc = 0.f;
    for (int p = tid; p < HW; p += 256) acc += logf(rowsf[n * HW + p]);
    __shared__ float s4[4];
    acc = blockReduceSum(acc, s4);
    if (tid == 0) {
        float f = -0.1f * acc / 1024.0f + 0.1f * sqrtf(scal[1]) / 1048576.0f;
        outreg[n] = 0.1f * scal[0] + f;
    }
}

__global__ void k_appnp_t(const float* __restrict__ ori, const float* __restrict__ wa1,
                          const float* __restrict__ ba1, const float* __restrict__ wa2,
                          const float* __restrict__ ba2, float* __restrict__ T) {
    int p = blockIdx.x, n = blockIdx.y, tid = threadIdx.x;
    const float* x = ori + (size_t)n * C * HW + (size_t)p * C;
    float xv = x[tid];
    __shared__ float s4[4];
    __shared__ float h[3];
    float d0 = blockReduceSum(xv * wa1[0 * C + tid], s4);
    float d1 = blockReduceSum(xv * wa1[1 * C + tid], s4);
    float d2 = blockReduceSum(xv * wa1[2 * C + tid], s4);
    if (tid == 0) {
        h[0] = fmaxf(d0 + ba1[0], 0.f);
        h[1] = fmaxf(d1 + ba1[1], 0.f);
        h[2] = fmaxf(d2 + ba1[2], 0.f);
    }
    __syncthreads();
    float t = h[0] * wa2[tid * 3 + 0] + h[1] * wa2[tid * 3 + 1] + h[2] * wa2[tid * 3 + 2] + ba2[tid];
    T[(size_t)n * HW * C + (size_t)p * C + tid] = fmaxf(t, 0.f);
}

// ================= DIAGNOSTICS (scratch-only; verdict via rocprof spin kernels) =================

// MFMA GCN-step variant. VAR bit0: swapped C/D intra-tile mapping. VAR bit1: B staged A-style (no tr_read).
// Computes S = relu(A@B + e1[row]) + e2[row][col], A=[256xK], B=[Kx1024], split-bf16 (~f32 accurate).
template<int VAR>
__global__ __launch_bounds__(256) void k_mfma_diag(
    const float* __restrict__ Af, int lda,
    const float* __restrict__ Bf, int ldb,
    int K,
    float* __restrict__ Cf, int ldc,
    const float* __restrict__ e1,
    const float* __restrict__ e2) {
    constexpr int BM = 64, BN = 128;
    constexpr int WM = BM / 32, WN = BN / 32;
    constexpr int ALO = BM * 64, BLO = 64 * BN;
    __shared__ __align__(16) u16 smA[2 * BM * 64];
    __shared__ __align__(16) u16 smB[2 * 64 * BN];
    int q0 = blockIdx.x * BN, m0 = blockIdx.y * BM;
    int tid = threadIdx.x, lane = tid & 63, wv = tid >> 6;
    int wm = wv >> 1, wn = wv & 1;

    f32x4 acc[WM][WN];
    #pragma unroll
    for (int mi = 0; mi < WM; ++mi)
        #pragma unroll
        for (int ni = 0; ni < WN; ++ni)
            acc[mi][ni] = (f32x4){0.f, 0.f, 0.f, 0.f};

    unsigned baseB = (unsigned)(size_t)(&smB[0]);
    unsigned trlane = baseB + 2u * ((lane & 15) + ((lane >> 4) << 6));

    for (int kt = 0; kt < K; kt += 64) {
        #pragma unroll
        for (int p = 0; p < BM / 32; ++p) {
            int e = (p * 256 + tid) * 8;
            int r = e >> 6, k = e & 63;
            int k5 = k & 31;
            int base = ((r >> 4) * 2 + (k >> 5)) * 512 + ((r & 15) + ((k5 & 15) >> 2) * 16) * 8 + (k5 >> 4) * 4;
            const float* src = Af + (size_t)(m0 + r) * lda + kt + k;
            float4 w0 = *(const float4*)src;
            float4 w1 = *(const float4*)(src + 4);
            float xs[8] = {w0.x, w0.y, w0.z, w0.w, w1.x, w1.y, w1.z, w1.w};
            short h[8], l[8];
            #pragma unroll
            for (int j = 0; j < 8; ++j) splitbf(xs[j], h[j], l[j]);
            *(bf16x4*)(smA + base)             = (bf16x4){h[0], h[1], h[2], h[3]};
            *(bf16x4*)(smA + base + 128)       = (bf16x4){h[4], h[5], h[6], h[7]};
            *(bf16x4*)(smA + ALO + base)       = (bf16x4){l[0], l[1], l[2], l[3]};
            *(bf16x4*)(smA + ALO + base + 128) = (bf16x4){l[4], l[5], l[6], l[7]};
        }
        #pragma unroll
        for (int p = 0; p < BN / 32; ++p) {
            int e = (p * 256 + tid) * 8;
            int kb = e / BN, c0 = e % BN;
            const float* src = Bf + (size_t)(kt + kb) * ldb + q0 + c0;
            float4 w0 = *(const float4*)src;
            float4 w1 = *(const float4*)(src + 4);
            float xs[8] = {w0.x, w0.y, w0.z, w0.w, w1.x, w1.y, w1.z, w1.w};
            short h[8], l[8];
            #pragma unroll
            for (int j = 0; j < 8; ++j) splitbf(xs[j], h[j], l[j]);
            if ((VAR & 2) == 0) {
                int sub = ((kb >> 4) * (BN / 16) + (c0 >> 4)) * 256 + (kb & 15) * 16 + (c0 & 15);
                *(bf16x8*)(smB + sub)       = (bf16x8){h[0], h[1], h[2], h[3], h[4], h[5], h[6], h[7]};
                *(bf16x8*)(smB + BLO + sub) = (bf16x8){l[0], l[1], l[2], l[3], l[4], l[5], l[6], l[7]};
            } else {
                int k5 = kb & 31;
                int g = (k5 & 15) >> 2;
                int basepos = ((c0 >> 4) * 2 + (kb >> 5)) * 512 + g * 128 + (k5 >> 4) * 4 + (k5 & 3);
                #pragma unroll
                for (int j = 0; j < 8; ++j) {
                    int pos = basepos + ((c0 + j) & 15) * 8;
                    smB[pos] = (u16)h[j];
                    smB[BLO + pos] = (u16)l[j];
                }
            }
        }
        __syncthreads();
        #pragma unroll
        for (int kk = 0; kk < 2; ++kk) {
            bf16x8 aH[WM], aL[WM], bH[WN], bL[WN];
            #pragma unroll
            for (int mi = 0; mi < WM; ++mi) {
                int s = ((wm * WM + mi) * 2 + kk) * 512;
                aH[mi] = *(const bf16x8*)(smA + s + lane * 8);
                aL[mi] = *(const bf16x8*)(smA + ALO + s + lane * 8);
            }
            if ((VAR & 2) == 0) {
                bf16x4 loH[WN], hiH[WN], loL[WN], hiL[WN];
                #pragma unroll
                for (int ni = 0; ni < WN; ++ni) {
                    int cc = wn * WN + ni;
                    unsigned a0 = trlane + (unsigned)(((kk * 2) * (BN / 16) + cc) * 512);
                    unsigned a1 = a0 + (BN / 16) * 512;
                    asm volatile("ds_read_b64_tr_b16 %0, %1" : "=v"(loH[ni]) : "v"(a0) : "memory");
                    asm volatile("ds_read_b64_tr_b16 %0, %1" : "=v"(hiH[ni]) : "v"(a1) : "memory");
                    asm volatile("ds_read_b64_tr_b16 %0, %1" : "=v"(loL[ni]) : "v"(a0 + 2u * BLO) : "memory");
                    asm volatile("ds_read_b64_tr_b16 %0, %1" : "=v"(hiL[ni]) : "v"(a1 + 2u * BLO) : "memory");
                }
                asm volatile("s_waitcnt lgkmcnt(0)" ::: "memory");
                __builtin_amdgcn_sched_barrier(0);
                #pragma unroll
                for (int ni = 0; ni < WN; ++ni) {
                    bH[ni] = __builtin_shufflevector(loH[ni], hiH[ni], 0, 1, 2, 3, 4, 5, 6, 7);
                    bL[ni] = __builtin_shufflevector(loL[ni], hiL[ni], 0, 1, 2, 3, 4, 5, 6, 7);
                }
            } else {
                #pragma unroll
                for (int ni = 0; ni < WN; ++ni) {
                    int cc = wn * WN + ni;
                    int s = (cc * 2 + kk) * 512 + lane * 8;
                    bH[ni] = *(const bf16x8*)(smB + s);
                    bL[ni] = *(const bf16x8*)(smB + BLO + s);
                }
            }
            #pragma unroll
            for (int mi = 0; mi < WM; ++mi)
                #pragma unroll
                for (int ni = 0; ni < WN; ++ni) {
                    acc[mi][ni] = __builtin_amdgcn_mfma_f32_16x16x32_bf16(aH[mi], bH[ni], acc[mi][ni], 0, 0, 0);
                    acc[mi][ni] = __builtin_amdgcn_mfma_f32_16x16x32_bf16(aH[mi], bL[ni], acc[mi][ni], 0, 0, 0);
                    acc[mi][ni] = __builtin_amdgcn_mfma_f32_16x16x32_bf16(aL[mi], bH[ni], acc[mi][ni], 0, 0, 0);
                }
        }
        __syncthreads();
    }

    int col0 = q0 + wn * (WN * 16);
    int row0 = m0 + wm * (WM * 16);
    #pragma unroll
    for (int mi = 0; mi < WM; ++mi) {
        #pragma unroll
        for (int ni = 0; ni < WN; ++ni) {
            #pragma unroll
            for (int r = 0; r < 4; ++r) {
                int rr, cc2;
                if (VAR & 1) {
                    rr  = row0 + mi * 16 + (lane & 15);
                    cc2 = col0 + ni * 16 + (lane >> 4) * 4 + r;
                } else {
                    rr  = row0 + mi * 16 + (lane >> 4) * 4 + r;
                    cc2 = col0 + ni * 16 + (lane & 15);
                }
                float val = acc[mi][ni][r];
                val = fmaxf(val + e1[rr], 0.f) + e2[(size_t)rr * ldc + cc2];
                Cf[(size_t)rr * ldc + cc2] = val;
            }
        }
    }
}

// tiled symmetrize diag (in place on a COPY), threshold included, fused rowsums -> dsum
__global__ void k_symB_tiled_diag(float* __restrict__ B, float* __restrict__ dsum) {
    int pi = blockIdx.x, tid = threadIdx.x;
    int i = 0, base = 0;
    while (pi >= base + (16 - i)) { base += 16 - i; ++i; }
    int j = i + (pi - base);
    int i0 = i * 64, j0 = j * 64;
    __shared__ float T1[64][65], T2[64][65];
    for (int idx = tid; idx < 4096; idx += 256) {
        int r = idx >> 6, c = idx & 63;
        float a = B[(size_t)(i0 + r) * HW + (j0 + c)];
        float b = B[(size_t)(j0 + r) * HW + (i0 + c)];
        T1[r][c] = a < 0.15f ? 0.f : a;
        T2[r][c] = b < 0.15f ? 0.f : b;
    }
    __syncthreads();
    for (int idx = tid; idx < 4096; idx += 256) {
        int r = idx >> 6, c = idx & 63;
        B[(size_t)(i0 + r) * HW + (j0 + c)] = 0.5f * (T1[r][c] + T2[c][r]);
    }
    if (i != j) {
        for (int idx = tid; idx < 4096; idx += 256) {
            int r = idx >> 6, c = idx & 63;
            B[(size_t)(j0 + r) * HW + (i0 + c)] = 0.5f * (T2[r][c] + T1[c][r]);
        }
    }
    if (tid < 64) {
        float s = 0.f;
        #pragma unroll 4
        for (int c = 0; c < 64; ++c) s += 0.5f * (T1[tid][c] + T2[c][tid]);
        atomicAdd(&dsum[i0 + tid], s);
    } else if (tid < 128 && i != j) {
        int t = tid - 64;
        float s = 0.f;
        #pragma unroll 4
        for (int c = 0; c < 64; ++c) s += 0.5f * (T2[t][c] + T1[c][t]);
        atomicAdd(&dsum[j0 + t], s);
    }
}

// checker helpers: spin ~0.8ms iff mismatch (verdict readable in rocprof top-5)
__device__ __forceinline__ float chk_maxdiff(const float* a, const float* b, int n, float* s4) {
    float md = 0.f;
    for (int i = threadIdx.x; i < n; i += 256) md = fmaxf(md, fabsf(a[i] - b[i]));
    return blockReduceMax(md, s4);
}
__device__ __forceinline__ void chk_spin(float bad, float* sink) {
    if (bad > 0.f) {
        float x = 1.0f;
        for (int k = 0; k < 500000; ++k) x = __builtin_fmaf(x, 0.99999988f, 1.0e-7f);
        if (threadIdx.x == 0) sink[0] = x;
    }
    if (threadIdx.x == 0) sink[1] = bad;
}
#define MAKE_CHK(NAME) \
__global__ void NAME(const float* a, const float* b, int n, float* sink) { \
    __shared__ float s4[4]; \
    float md = chk_maxdiff(a, b, n, s4); \
    chk_spin(md - 0.05f, sink); }
MAKE_CHK(k_chk_v0)
MAKE_CHK(k_chk_v1)
MAKE_CHK(k_chk_v2)
MAKE_CHK(k_chk_v3)

__global__ void k_chk_sym(const float* Bprod, const float* Bdiag,
                          const float* dsinv_prod, const float* dsum2, float* sink) {
    __shared__ float s4[4];
    float md1 = chk_maxdiff(Bprod, Bdiag, HW * HW, s4);
    float md2 = 0.f;
    for (int p = threadIdx.x; p < HW; p += 256) {
        float d = fabsf(dsinv_prod[p] - 1.0f / sqrtf(dsum2[p] + 1.0f));
        md2 = fmaxf(md2, d);
    }
    md2 = blockReduceMax(md2, s4);
    if (threadIdx.x == 0) { sink[2] = md1; sink[3] = md2; }
    chk_spin(fmaxf(md1 - 1e-4f, md2 - 1e-3f), sink);
}

// =====================================================================================
extern "C" void kernel_launch(void* const* d_in, const int* in_sizes, int n_in,
                              void* d_out, int out_size, void* d_ws, size_t ws_size,
                              hipStream_t stream) {
    const float* seg_in = (const float*)d_in[0];
    const float* edge   = (const float*)d_in[1];
    const float* ws1    = (const float*)d_in[2];
    const float* bs1    = (const float*)d_in[3];
    const float* ws11   = (const float*)d_in[4];
    const float* bs11   = (const float*)d_in[5];
    const float* ws2    = (const float*)d_in[6];
    const float* bs2    = (const float*)d_in[7];
    const float* ws3    = (const float*)d_in[8];
    const float* bs3    = (const float*)d_in[9];
    const float* wmlp   = (const float*)d_in[10];
    const float* bmlp   = (const float*)d_in[11];
    const float* wgcn   = (const float*)d_in[12];
    const float* bgcn   = (const float*)d_in[13];
    const float* wa1    = (const float*)d_in[14];
    const float* ba1    = (const float*)d_in[15];
    const float* wa2    = (const float*)d_in[16];
    const float* ba2    = (const float*)d_in[17];

    float* out = (float*)d_out;
    float* w = (float*)d_ws;
    float* SEG_A   = w; w += (size_t)NB * C * HW;
    float* SEG_SIM = w; w += (size_t)NB * C * HW;
    float* SEGS    = w; w += (size_t)NB * NS * HW;
    float* SEGC    = w; w += (size_t)NB * NS * HW;
    float* TBUF    = w; w += (size_t)NB * HW * C;
    float* OBUF    = w; w += (size_t)NB * HW * C;
    float* BBUF    = w; w += (size_t)NB * HW * HW;
    float* ACCUM   = w; w += (size_t)NB * HW * HW;
    float* ubuf    = w; w += NB * HW;
    float* vbuf    = w; w += NB * HW;
    float* ssbuf   = w; w += NB * HW;
    float* embuf   = w; w += NB * HW;
    float* dcinv   = w; w += NB * HW;
    float* dsinv   = w; w += NB * HW;
    float* dfinv   = w; w += NB * HW;
    float* rowsf   = w; w += NB * HW;
    float* diagrow = w; w += NB * HW;
    float* sqrow   = w; w += NB * HW;
    float* pooled  = w; w += NB * C;
    float* cabuf   = w; w += NB * NS;
    float* scal    = w; w += 64;
    // diagnostic scratch
    float* S1      = w; w += (size_t)C * HW;
    float* S2      = w; w += (size_t)C * HW;
    float* S3      = w; w += (size_t)C * HW;
    float* S4      = w; w += (size_t)C * HW;
    float* SYMC    = w; w += (size_t)HW * HW;
    float* dsum2   = w; w += HW;
    float* sink    = w; w += 64;

    const long long sAdj = (long long)HW * HW;
    const long long sSeg = (long long)C * HW;
    const long long sSgs = (long long)NS * HW;

    for (int it = 0; it < 3; ++it) {
        const float* seg_src = (it == 0) ? seg_in : SEG_A;
        k_conv_sc<<<dim3(NS, NB), 256, 0, stream>>>(seg_src, ws1, bs1, ws11, bs11, SEGS, SEGC);
        k_pooled<<<dim3(C, NB), 256, 0, stream>>>(seg_src, pooled);
        k_ca<<<dim3(NB), 64, 0, stream>>>(pooled, wmlp, bmlp, cabuf);
        k_vecs<<<dim3(4, NB, 4), 256, 0, stream>>>(seg_src, edge, SEGS, cabuf,
                                                   ws2, bs2, ws3, bs3,
                                                   ubuf, vbuf, ssbuf, embuf);
        k_gemm64<1><<<dim3(16, 16, NB), 256, 0, stream>>>(SEGC, sSgs, NS, SEGC, sSgs, HW,
                                                          BBUF, sAdj, HW, NS,
                                                          embuf, HW, ssbuf, HW);
        if (it == 0) {
            // snapshot pre-sym B (n=0) for the tiled-symB equivalence test
            hipMemcpyAsync(SYMC, BBUF, (size_t)HW * HW * sizeof(float),
                           hipMemcpyDeviceToDevice, stream);
            hipMemsetAsync(dsum2, 0, HW * sizeof(float), stream);
        }
        k_symB<<<dim3(HW, NB), 256, 0, stream>>>(BBUF);
        k_rowsum_cs<<<dim3(HW, NB), 256, 0, stream>>>(BBUF, ubuf, vbuf, dcinv, dsinv);
        if (it == 0) {
            k_symB_tiled_diag<<<dim3(136), 256, 0, stream>>>(SYMC, dsum2);
            k_chk_sym<<<dim3(1), 256, 0, stream>>>(BBUF, SYMC, dsinv, dsum2, sink + 16);
        }
        k_build_sim<<<dim3(HW, NB), 256, 0, stream>>>(BBUF, ubuf, vbuf, dcinv, dsinv, dfinv);
        k_norm_accum<<<dim3(HW, NB), 256, 0, stream>>>(BBUF, dfinv, ACCUM, it == 0 ? 1 : 0);
        k_gemm64<0><<<dim3(16, 4, NB), 256, 0, stream>>>(seg_src, sSeg, HW, BBUF, sAdj, HW,
                                                         SEG_SIM, sSeg, HW, HW,
                                                         nullptr, 0, nullptr, 0);
        k_gemm64<2><<<dim3(16, 4, NB), 256, 0, stream>>>(wgcn, 0, C, SEG_SIM, sSeg, HW,
                                                         SEG_A, sSeg, HW, C,
                                                         bgcn, 0, seg_src, sSeg);
        if (it == 0) {
            // MFMA variants on the exact GCN step (n=0); ref = production SEG_A (n=0)
            k_mfma_diag<0><<<dim3(8, 4, 1), 256, 0, stream>>>(wgcn, C, SEG_SIM, HW, C, S1, HW, bgcn, seg_in);
            k_mfma_diag<1><<<dim3(8, 4, 1), 256, 0, stream>>>(wgcn, C, SEG_SIM, HW, C, S2, HW, bgcn, seg_in);
            k_mfma_diag<2><<<dim3(8, 4, 1), 256, 0, stream>>>(wgcn, C, SEG_SIM, HW, C, S3, HW, bgcn, seg_in);
            k_mfma_diag<3><<<dim3(8, 4, 1), 256, 0, stream>>>(wgcn, C, SEG_SIM, HW, C, S4, HW, bgcn, seg_in);
            k_chk_v0<<<dim3(1), 256, 0, stream>>>(SEG_A, S1, C * HW, sink + 0);
            k_chk_v1<<<dim3(1), 256, 0, stream>>>(SEG_A, S2, C * HW, sink + 4);
            k_chk_v2<<<dim3(1), 256, 0, stream>>>(SEG_A, S3, C * HW, sink + 8);
            k_chk_v3<<<dim3(1), 256, 0, stream>>>(SEG_A, S4, C * HW, sink + 12);
        }
    }

    k_final_rowsum<<<dim3(HW, NB), 256, 0, stream>>>(ACCUM, dcinv);
    k_final_norm<<<dim3(HW, NB), 256, 0, stream>>>(ACCUM, dcinv, rowsf, diagrow, sqrow);
    k_scal<<<dim3(1), 256, 0, stream>>>(diagrow, sqrow, scal);
    k_reg<<<dim3(NB), 256, 0, stream>>>(rowsf, scal, out + (size_t)NB * C * HW);

    k_appnp_t<<<dim3(HW, NB), 256, 0, stream>>>(seg_in, wa1, ba1, wa2, ba2, TBUF);
    k_gemm64<3><<<dim3(4, 16, NB), 256, 0, stream>>>(ACCUM, sAdj, HW, TBUF, (long long)HW * C, C,
                                                     out, (long long)HW * C, C, HW,
                                                     nullptr, 0, TBUF, (long long)HW * C);
    k_gemm64<3><<<dim3(4, 16, NB), 256, 0, stream>>>(ACCUM, sAdj, HW, out, (long long)HW * C, C,
                                                     OBUF, (long long)HW * C, C, HW,
                                                     nullptr, 0, TBUF, (long long)HW * C);
    k_gemm64<3><<<dim3(4, 16, NB), 256, 0, stream>>>(ACCUM, sAdj, HW, OBUF, (long long)HW * C, C,
                                                     out, (long long)HW * C, C, HW,
                                                     nullptr, 0, TBUF, (long long)HW * C);
}

// Round 8
// 1072.712 us; speedup vs baseline: 2.6739x; 2.6739x over previous
//
#include <hip/hip_runtime.h>
#include <math.h>

#define NB 8
#define C 256
#define HW 1024
#define NS 64

typedef unsigned short u16;
typedef __attribute__((ext_vector_type(8))) short bf16x8;
typedef __attribute__((ext_vector_type(4))) float f32x4;

__device__ __forceinline__ u16 f2bf(float x) {
    union { float f; unsigned u; } v; v.f = x;
    unsigned r = v.u + 0x7fffu + ((v.u >> 16) & 1u);
    return (u16)(r >> 16);
}
__device__ __forceinline__ float bf2f(u16 h) {
    union { unsigned u; float f; } v; v.u = ((unsigned)h) << 16; return v.f;
}
__device__ __forceinline__ void splitbf(float x, u16& h, u16& l) {
    h = f2bf(x);
    l = f2bf(x - bf2f(h));
}

// ---------------- block reduction helper ----------------
__device__ __forceinline__ float blockReduceSum(float v, float* s4) {
    #pragma unroll
    for (int o = 32; o; o >>= 1) v += __shfl_down(v, o);
    __syncthreads();
    if ((threadIdx.x & 63) == 0) s4[threadIdx.x >> 6] = v;
    __syncthreads();
    return s4[0] + s4[1] + s4[2] + s4[3];
}

// ================= r5-verified pipeline kernels =================

__global__ void k_conv_sc(const float* __restrict__ seg,
                          const float* __restrict__ ws1, const float* __restrict__ bs1,
                          const float* __restrict__ ws11, const float* __restrict__ bs11,
                          float* __restrict__ seg_s, float* __restrict__ seg_c) {
    int s = blockIdx.x, n = blockIdx.y, tid = threadIdx.x;
    __shared__ float w1[C], w2[C];
    w1[tid] = ws1[s * C + tid];
    w2[tid] = ws11[s * C + tid];
    __syncthreads();
    const float* sb = seg + (size_t)n * C * HW;
    float a0 = 0, a1 = 0, a2 = 0, a3 = 0, b0 = 0, b1 = 0, b2 = 0, b3 = 0;
    for (int c = 0; c < C; ++c) {
        const float* row = sb + (size_t)c * HW;
        float w1c = w1[c], w2c = w2[c];
        float s0 = row[tid], s1 = row[tid + 256], s2 = row[tid + 512], s3 = row[tid + 768];
        a0 += s0 * w1c; a1 += s1 * w1c; a2 += s2 * w1c; a3 += s3 * w1c;
        b0 += s0 * w2c; b1 += s1 * w2c; b2 += s2 * w2c; b3 += s3 * w2c;
    }
    float bias1 = bs1[s], bias2 = bs11[s];
    float* o1 = seg_s + ((size_t)n * NS + s) * HW;
    float* o2 = seg_c + ((size_t)n * NS + s) * HW;
    o1[tid] = a0 + bias1; o1[tid + 256] = a1 + bias1; o1[tid + 512] = a2 + bias1; o1[tid + 768] = a3 + bias1;
    o2[tid] = b0 + bias2; o2[tid + 256] = b1 + bias2; o2[tid + 512] = b2 + bias2; o2[tid + 768] = b3 + bias2;
}

__global__ void k_pooled(const float* __restrict__ seg, float* __restrict__ pooled) {
    int c = blockIdx.x, n = blockIdx.y, tid = threadIdx.x;
    const float* row = seg + ((size_t)n * C + c) * HW;
    float acc = row[tid] + row[tid + 256] + row[tid + 512] + row[tid + 768];
    __shared__ float s4[4];
    float r = blockReduceSum(acc, s4);
    if (tid == 0) pooled[n * C + c] = r * (1.0f / HW);
}

__global__ void k_ca(const float* __restrict__ pooled, const float* __restrict__ wmlp,
                     const float* __restrict__ bmlp, float* __restrict__ ca) {
    int n = blockIdx.x, s = threadIdx.x;
    __shared__ float pl[C];
    for (int i = s; i < C; i += 64) pl[i] = pooled[n * C + i];
    __syncthreads();
    float acc = 0.f;
    for (int c = 0; c < C; ++c) acc += pl[c] * wmlp[s * C + c];
    float r = acc + bmlp[s];
    ca[n * NS + s] = r > 0.f ? r : 0.f;
}

__global__ void k_vecs(const float* __restrict__ seg, const float* __restrict__ edge,
                       const float* __restrict__ seg_s, const float* __restrict__ ca,
                       const float* __restrict__ ws2, const float* __restrict__ bs2,
                       const float* __restrict__ ws3, const float* __restrict__ bs3,
                       float* __restrict__ u, float* __restrict__ vv,
                       float* __restrict__ segss, float* __restrict__ edgemm) {
    int pos = blockIdx.x * 256 + threadIdx.x;
    int n = blockIdx.y, role = blockIdx.z;
    if (role == 0) {
        __shared__ float cs[NS];
        if (threadIdx.x < NS) cs[threadIdx.x] = ca[n * NS + threadIdx.x];
        __syncthreads();
        const float* base = seg_s + (size_t)n * NS * HW + (size_t)pos * NS;
        float acc = 0.f;
        #pragma unroll
        for (int s = 0; s < NS; ++s) acc += base[s] * cs[s];
        u[n * HW + pos] = acc;
    } else if (role == 1) {
        __shared__ float cs[NS];
        if (threadIdx.x < NS) cs[threadIdx.x] = ca[n * NS + threadIdx.x];
        __syncthreads();
        const float* base = seg_s + (size_t)n * NS * HW + pos;
        float acc = 0.f;
        #pragma unroll
        for (int s = 0; s < NS; ++s) acc += cs[s] * base[(size_t)s * HW];
        vv[n * HW + pos] = acc;
    } else if (role == 2) {
        const float* base = seg + (size_t)n * C * HW + pos;
        float m = -3.402823466e38f;
        for (int c = 0; c < C; ++c) m = fmaxf(m, base[(size_t)c * HW]);
        segss[n * HW + pos] = ws2[0] * m + bs2[0];
    } else {
        const float* sb = seg + (size_t)n * C * HW + pos;
        const float* eb = edge + (size_t)n * C * HW + pos;
        float m = -3.402823466e38f;
        for (int c = 0; c < C; ++c) m = fmaxf(m, sb[(size_t)c * HW] * eb[(size_t)c * HW]);
        edgemm[n * HW + pos] = ws3[0] * m + bs3[0];
    }
}

// f32 vector GEMM — kept ONLY for B-build (MODE 1), unchanged from r5
template <int MODE>
__global__ void k_gemm64(const float* __restrict__ A, long long strideA, int lda,
                         const float* __restrict__ Bm, long long strideB, int ldb,
                         float* __restrict__ Cm, long long strideC, int ldc, int K,
                         const float* __restrict__ e1, long long se1,
                         const float* __restrict__ e2, long long se2) {
    int n = blockIdx.z;
    int m0 = blockIdx.y * 64, q0 = blockIdx.x * 64;
    const float* Ab = A + (size_t)n * strideA;
    const float* Bb = Bm + (size_t)n * strideB;
    float* Cb = Cm + (size_t)n * strideC;
    __shared__ float As[64][33];
    __shared__ float Bs[32][64];
    int tid = threadIdx.x, tx = tid & 15, ty = tid >> 4;
    float acc[4][4] = {};
    for (int k0 = 0; k0 < K; k0 += 32) {
        #pragma unroll
        for (int i = 0; i < 8; ++i) {
            int e = tid + i * 256;
            int ml = e >> 5, kl = e & 31;
            As[ml][kl] = Ab[(size_t)(m0 + ml) * lda + k0 + kl];
        }
        #pragma unroll
        for (int i = 0; i < 8; ++i) {
            int e = tid + i * 256;
            int kl = e >> 6, nl = e & 63;
            Bs[kl][nl] = Bb[(size_t)(k0 + kl) * ldb + q0 + nl];
        }
        __syncthreads();
        #pragma unroll
        for (int kk = 0; kk < 32; ++kk) {
            float a0 = As[ty * 4 + 0][kk], a1 = As[ty * 4 + 1][kk];
            float a2 = As[ty * 4 + 2][kk], a3 = As[ty * 4 + 3][kk];
            float4 b = *(const float4*)&Bs[kk][tx * 4];
            acc[0][0] += a0 * b.x; acc[0][1] += a0 * b.y; acc[0][2] += a0 * b.z; acc[0][3] += a0 * b.w;
            acc[1][0] += a1 * b.x; acc[1][1] += a1 * b.y; acc[1][2] += a1 * b.z; acc[1][3] += a1 * b.w;
            acc[2][0] += a2 * b.x; acc[2][1] += a2 * b.y; acc[2][2] += a2 * b.z; acc[2][3] += a2 * b.w;
            acc[3][0] += a3 * b.x; acc[3][1] += a3 * b.y; acc[3][2] += a3 * b.z; acc[3][3] += a3 * b.w;
        }
        __syncthreads();
    }
    #pragma unroll
    for (int i = 0; i < 4; ++i) {
        int m = m0 + ty * 4 + i;
        float* crow = Cb + (size_t)m * ldc + q0 + tx * 4;
        #pragma unroll
        for (int j = 0; j < 4; ++j) {
            int q = q0 + tx * 4 + j;
            float val = acc[i][j];
            if (MODE == 1) {
                val *= e1[(size_t)n * se1 + m] * e2[(size_t)n * se2 + q];
            }
            crow[j] = val;
        }
    }
}

// ===================== MFMA split-bf16 NT-GEMM: C = A * Bsrc^T =====================
// Both operands staged ROW-MAJOR in LDS; fragments read as plain contiguous 8-k runs:
//   slot t of lane l  <->  k = 8*(l>>4) + t    (same map for A and B -> pairing-invariant)
// C/D layout (m89 HW-verified): reg r of lane l -> row = (l>>4)*4 + r, col = l&15.
// Split precision: acc = aH*bH + aH*bL + aL*bH  (~f32 accuracy).
// Semantics: C[m][q] = sum_k A[m][k] * Bsrc[q][k]
// MODE 0: write Ct[col*ldc + row] = acc                      (transposed store)
// MODE 2: C[row*ldc+col] = relu(acc + e1[row]) + e2[n][row*ldc+col]
// MODE 3: C[row*ldc+col] = 0.5*acc + 0.5*e2[n][row*ldc+col]
// MODE 4: Ct[col*ldc + row] = 0.5*acc + 0.5*e2[n][row*HW+col]  (final APPNP -> out)
template<int BM, int BN, int MODE>
__global__ __launch_bounds__(256) void k_mfma2(
    const float* __restrict__ Af, long long sA, int lda,
    const float* __restrict__ Bf, long long sB, int ldb,
    int K,
    float* __restrict__ Cf, long long sCf, int ldc,
    const float* __restrict__ e1,
    const float* __restrict__ e2, long long se2) {
    constexpr int WM = BM / 32;           // 16-row subtiles per wave (M)
    constexpr int WN = BN / 32;           // 16-col subtiles per wave (N)
    constexpr int LDK = 72;               // padded k-stride (u16); 144B rows, 16B-aligned
    __shared__ __align__(16) u16 sAH[BM * LDK], sAL[BM * LDK];
    __shared__ __align__(16) u16 sBH[BN * LDK], sBL[BN * LDK];
    int n = blockIdx.z;
    int q0 = blockIdx.x * BN, m0 = blockIdx.y * BM;
    int tid = threadIdx.x, lane = tid & 63, wv = tid >> 6;
    int wm = wv >> 1, wn = wv & 1;

    f32x4 acc[WM][WN];
    #pragma unroll
    for (int mi = 0; mi < WM; ++mi)
        #pragma unroll
        for (int ni = 0; ni < WN; ++ni)
            acc[mi][ni] = (f32x4){0.f, 0.f, 0.f, 0.f};

    for (int kt = 0; kt < K; kt += 64) {
        // ---- stage A tile [BM][64], row-major, hi/lo split ----
        #pragma unroll
        for (int p = 0; p < BM / 32; ++p) {
            int e = (p * 256 + tid) * 8;          // element id, multiple of 8
            int r = e >> 6, k0 = e & 63;
            const float* src = Af + (size_t)n * sA + (size_t)(m0 + r) * lda + kt + k0;
            float4 w0 = *(const float4*)src;
            float4 w1 = *(const float4*)(src + 4);
            float xs[8] = {w0.x, w0.y, w0.z, w0.w, w1.x, w1.y, w1.z, w1.w};
            u16 h[8], l[8];
            #pragma unroll
            for (int j = 0; j < 8; ++j) splitbf(xs[j], h[j], l[j]);
            int base = r * LDK + k0;
            *(bf16x8*)(sAH + base) = (bf16x8){(short)h[0], (short)h[1], (short)h[2], (short)h[3],
                                              (short)h[4], (short)h[5], (short)h[6], (short)h[7]};
            *(bf16x8*)(sAL + base) = (bf16x8){(short)l[0], (short)l[1], (short)l[2], (short)l[3],
                                              (short)l[4], (short)l[5], (short)l[6], (short)l[7]};
        }
        // ---- stage B tile [BN][64] (rows of Bsrc), row-major, hi/lo split ----
        #pragma unroll
        for (int p = 0; p < BN / 32; ++p) {
            int e = (p * 256 + tid) * 8;
            int c = e >> 6, k0 = e & 63;
            const float* src = Bf + (size_t)n * sB + (size_t)(q0 + c) * ldb + kt + k0;
            float4 w0 = *(const float4*)src;
            float4 w1 = *(const float4*)(src + 4);
            float xs[8] = {w0.x, w0.y, w0.z, w0.w, w1.x, w1.y, w1.z, w1.w};
            u16 h[8], l[8];
            #pragma unroll
            for (int j = 0; j < 8; ++j) splitbf(xs[j], h[j], l[j]);
            int base = c * LDK + k0;
            *(bf16x8*)(sBH + base) = (bf16x8){(short)h[0], (short)h[1], (short)h[2], (short)h[3],
                                              (short)h[4], (short)h[5], (short)h[6], (short)h[7]};
            *(bf16x8*)(sBL + base) = (bf16x8){(short)l[0], (short)l[1], (short)l[2], (short)l[3],
                                              (short)l[4], (short)l[5], (short)l[6], (short)l[7]};
        }
        __syncthreads();
        #pragma unroll
        for (int kk = 0; kk < 2; ++kk) {
            int klocal = kk * 32 + (lane >> 4) * 8;
            bf16x8 aH[WM], aL[WM], bH[WN], bL[WN];
            #pragma unroll
            for (int mi = 0; mi < WM; ++mi) {
                int row = (wm * WM + mi) * 16 + (lane & 15);
                aH[mi] = *(const bf16x8*)(sAH + row * LDK + klocal);
                aL[mi] = *(const bf16x8*)(sAL + row * LDK + klocal);
            }
            #pragma unroll
            for (int ni = 0; ni < WN; ++ni) {
                int col = (wn * WN + ni) * 16 + (lane & 15);
                bH[ni] = *(const bf16x8*)(sBH + col * LDK + klocal);
                bL[ni] = *(const bf16x8*)(sBL + col * LDK + klocal);
            }
            #pragma unroll
            for (int mi = 0; mi < WM; ++mi)
                #pragma unroll
                for (int ni = 0; ni < WN; ++ni) {
                    acc[mi][ni] = __builtin_amdgcn_mfma_f32_16x16x32_bf16(aH[mi], bH[ni], acc[mi][ni], 0, 0, 0);
                    acc[mi][ni] = __builtin_amdgcn_mfma_f32_16x16x32_bf16(aH[mi], bL[ni], acc[mi][ni], 0, 0, 0);
                    acc[mi][ni] = __builtin_amdgcn_mfma_f32_16x16x32_bf16(aL[mi], bH[ni], acc[mi][ni], 0, 0, 0);
                }
        }
        __syncthreads();
    }

    // ---- epilogue (C/D: row=(lane>>4)*4+r, col=lane&15) ----
    #pragma unroll
    for (int mi = 0; mi < WM; ++mi) {
        #pragma unroll
        for (int ni = 0; ni < WN; ++ni) {
            int col = q0 + (wn * WN + ni) * 16 + (lane & 15);
            int rowb = m0 + (wm * WM + mi) * 16 + (lane >> 4) * 4;
            #pragma unroll
            for (int r = 0; r < 4; ++r) {
                int row = rowb + r;
                float val = acc[mi][ni][r];
                if (MODE == 0) {
                    Cf[(size_t)n * sCf + (size_t)col * ldc + row] = val;
                } else if (MODE == 2) {
                    val = fmaxf(val + e1[row], 0.f) + e2[(size_t)n * se2 + (size_t)row * ldc + col];
                    Cf[(size_t)n * sCf + (size_t)row * ldc + col] = val;
                } else if (MODE == 3) {
                    val = 0.5f * val + 0.5f * e2[(size_t)n * se2 + (size_t)row * ldc + col];
                    Cf[(size_t)n * sCf + (size_t)row * ldc + col] = val;
                } else {  // MODE 4: final APPNP, write out[pos][ch]
                    val = 0.5f * val + 0.5f * e2[(size_t)n * se2 + (size_t)row * HW + col];
                    Cf[(size_t)n * sCf + (size_t)col * ldc + row] = val;
                }
            }
        }
    }
}

// ---------------- transpose [1024 x 256] -> [256 x 1024] per image ----------------
__global__ void k_transpose(const float* __restrict__ in, float* __restrict__ outp) {
    int ti = blockIdx.x, tj = blockIdx.y, n = blockIdx.z, tid = threadIdx.x;
    int i0 = ti * 64, j0 = tj * 64;   // i over 1024 (rows of in), j over 256 (cols of in)
    const float* ib = in + (size_t)n * HW * C;
    float* ob = outp + (size_t)n * C * HW;
    __shared__ float L[64][65];
    for (int idx = tid; idx < 4096; idx += 256) {
        int r = idx >> 6, c = idx & 63;
        L[r][c] = ib[(size_t)(i0 + r) * C + (j0 + c)];
    }
    __syncthreads();
    for (int idx = tid; idx < 4096; idx += 256) {
        int r = idx >> 6, c = idx & 63;
        ob[(size_t)(j0 + r) * HW + (i0 + c)] = L[c][r];
    }
}

// ---------------- r5 adjacency/reduction kernels ----------------
__global__ void k_symB(float* __restrict__ B) {
    int p = blockIdx.x, n = blockIdx.y;
    float* Bb = B + (size_t)n * HW * HW;
    for (int q = p + threadIdx.x; q < HW; q += 256) {
        float x = Bb[(size_t)p * HW + q];
        float y = Bb[(size_t)q * HW + p];
        x = x < 0.15f ? 0.f : x;
        y = y < 0.15f ? 0.f : y;
        float m = 0.5f * (x + y);
        Bb[(size_t)p * HW + q] = m;
        Bb[(size_t)q * HW + p] = m;
    }
}

__global__ void k_rowsum_cs(const float* __restrict__ B, const float* __restrict__ u,
                            const float* __restrict__ vv, float* __restrict__ dcinv,
                            float* __restrict__ dsinv) {
    int p = blockIdx.x, n = blockIdx.y, tid = threadIdx.x;
    const float* Bb = B + (size_t)n * HW * HW + (size_t)p * HW;
    const float* un = u + n * HW;
    const float* vn = vv + n * HW;
    float up = un[p], vp = vn[p];
    float acc_s = 0.f, acc_c = 0.f;
    for (int q = tid; q < HW; q += 256) {
        acc_s += Bb[q];
        float x = up * vn[q]; x = x < 0.15f ? 0.f : x;
        float y = un[q] * vp; y = y < 0.15f ? 0.f : y;
        acc_c += 0.5f * (x + y);
    }
    __shared__ float s4[4];
    acc_s = blockReduceSum(acc_s, s4);
    acc_c = blockReduceSum(acc_c, s4);
    if (tid == 0) {
        dsinv[n * HW + p] = 1.0f / sqrtf(acc_s + 1.0f);
        dcinv[n * HW + p] = 1.0f / sqrtf(acc_c + 1.0f);
    }
}

__global__ void k_build_sim(float* __restrict__ B, const float* __restrict__ u,
                            const float* __restrict__ vv, const float* __restrict__ dcinv,
                            const float* __restrict__ dsinv, float* __restrict__ dfinv) {
    int p = blockIdx.x, n = blockIdx.y, tid = threadIdx.x;
    float* Bb = B + (size_t)n * HW * HW + (size_t)p * HW;
    const float* un = u + n * HW;
    const float* vn = vv + n * HW;
    const float* dci = dcinv + n * HW;
    const float* dsi = dsinv + n * HW;
    float up = un[p], vp = vn[p], dcp = dci[p], dsp = dsi[p];
    float acc = 0.f;
    for (int q = tid; q < HW; q += 256) {
        float x = up * vn[q]; x = x < 0.15f ? 0.f : x;
        float y = un[q] * vp; y = y < 0.15f ? 0.f : y;
        float delta = (q == p) ? 1.0f : 0.0f;
        float val = (0.5f * (x + y) + delta) * dcp * dci[q] + (Bb[q] + delta) * dsp * dsi[q];
        Bb[q] = val;
        acc += val;
    }
    __shared__ float s4[4];
    acc = blockReduceSum(acc, s4);
    if (tid == 0) dfinv[n * HW + p] = 1.0f / sqrtf(acc + 1.0f);
}

__global__ void k_norm_accum(float* __restrict__ B, const float* __restrict__ dfinv,
                             float* __restrict__ ACC, int first) {
    int p = blockIdx.x, n = blockIdx.y, tid = threadIdx.x;
    float* Bb = B + (size_t)n * HW * HW + (size_t)p * HW;
    float* Ab = ACC + (size_t)n * HW * HW + (size_t)p * HW;
    const float* df = dfinv + n * HW;
    float dfp = df[p];
    for (int q = tid; q < HW; q += 256) {
        float val = (Bb[q] + ((q == p) ? 1.f : 0.f)) * dfp * df[q];
        Bb[q] = val;
        Ab[q] = first ? val : (Ab[q] + val);
    }
}

__global__ void k_final_rowsum(const float* __restrict__ ACC, float* __restrict__ dinv) {
    int p = blockIdx.x, n = blockIdx.y, tid = threadIdx.x;
    const float* Ab = ACC + (size_t)n * HW * HW + (size_t)p * HW;
    float acc = 0.f;
    for (int q = tid; q < HW; q += 256) acc += Ab[q];
    __shared__ float s4[4];
    acc = blockReduceSum(acc, s4);
    if (tid == 0) dinv[n * HW + p] = 1.0f / sqrtf(acc * (1.0f / 3.0f) + 1.0f);
}

__global__ void k_final_norm(float* __restrict__ ACC, const float* __restrict__ dinv,
                             float* __restrict__ rowsf, float* __restrict__ diagrow,
                             float* __restrict__ sqrow) {
    int p = blockIdx.x, n = blockIdx.y, tid = threadIdx.x;
    float* Ab = ACC + (size_t)n * HW * HW + (size_t)p * HW;
    const float* di = dinv + n * HW;
    float dp = di[p];
    float accr = 0.f, accsq = 0.f, accd = 0.f;
    for (int q = tid; q < HW; q += 256) {
        float val = (Ab[q] * (1.0f / 3.0f) + ((q == p) ? 1.f : 0.f)) * dp * di[q];
        Ab[q] = val;
        accr += val;
        accsq += val * val;
        if (q == p) accd = val;
    }
    __shared__ float s4[4];
    accr = blockReduceSum(accr, s4);
    accsq = blockReduceSum(accsq, s4);
    accd = blockReduceSum(accd, s4);
    if (tid == 0) {
        rowsf[n * HW + p] = accr;
        sqrow[n * HW + p] = accsq;
        diagrow[n * HW + p] = accd;
    }
}

__global__ void k_scal(const float* __restrict__ diagrow, const float* __restrict__ sqrow,
                       float* __restrict__ scal) {
    int tid = threadIdx.x;
    float a = 0.f, b = 0.f;
    for (int i = tid; i < NB * HW; i += 256) { a += diagrow[i]; b += sqrow[i]; }
    __shared__ float s4[4];
    a = blockReduceSum(a, s4);
    b = blockReduceSum(b, s4);
    if (tid == 0) { scal[0] = a; scal[1] = b; }
}

__global__ void k_reg(const float* __restrict__ rowsf, const float* __restrict__ scal,
                      float* __restrict__ outreg) {
    int n = blockIdx.x, tid = threadIdx.x;
    float acc = 0.f;
    for (int p = tid; p < HW; p += 256) acc += logf(rowsf[n * HW + p]);
    __shared__ float s4[4];
    acc = blockReduceSum(acc, s4);
    if (tid == 0) {
        float f = -0.1f * acc / 1024.0f + 0.1f * sqrtf(scal[1]) / 1048576.0f;
        outreg[n] = 0.1f * scal[0] + f;
    }
}

__global__ void k_appnp_t(const float* __restrict__ ori, const float* __restrict__ wa1,
                          const float* __restrict__ ba1, const float* __restrict__ wa2,
                          const float* __restrict__ ba2, float* __restrict__ T) {
    int p = blockIdx.x, n = blockIdx.y, tid = threadIdx.x;
    const float* x = ori + (size_t)n * C * HW + (size_t)p * C;
    float xv = x[tid];
    __shared__ float s4[4];
    __shared__ float h[3];
    float d0 = blockReduceSum(xv * wa1[0 * C + tid], s4);
    float d1 = blockReduceSum(xv * wa1[1 * C + tid], s4);
    float d2 = blockReduceSum(xv * wa1[2 * C + tid], s4);
    if (tid == 0) {
        h[0] = fmaxf(d0 + ba1[0], 0.f);
        h[1] = fmaxf(d1 + ba1[1], 0.f);
        h[2] = fmaxf(d2 + ba1[2], 0.f);
    }
    __syncthreads();
    float t = h[0] * wa2[tid * 3 + 0] + h[1] * wa2[tid * 3 + 1] + h[2] * wa2[tid * 3 + 2] + ba2[tid];
    T[(size_t)n * HW * C + (size_t)p * C + tid] = fmaxf(t, 0.f);
}

// =====================================================================================
extern "C" void kernel_launch(void* const* d_in, const int* in_sizes, int n_in,
                              void* d_out, int out_size, void* d_ws, size_t ws_size,
                              hipStream_t stream) {
    const float* seg_in = (const float*)d_in[0];
    const float* edge   = (const float*)d_in[1];
    const float* ws1    = (const float*)d_in[2];
    const float* bs1    = (const float*)d_in[3];
    const float* ws11   = (const float*)d_in[4];
    const float* bs11   = (const float*)d_in[5];
    const float* ws2    = (const float*)d_in[6];
    const float* bs2    = (const float*)d_in[7];
    const float* ws3    = (const float*)d_in[8];
    const float* bs3    = (const float*)d_in[9];
    const float* wmlp   = (const float*)d_in[10];
    const float* bmlp   = (const float*)d_in[11];
    const float* wgcn   = (const float*)d_in[12];
    const float* bgcn   = (const float*)d_in[13];
    const float* wa1    = (const float*)d_in[14];
    const float* ba1    = (const float*)d_in[15];
    const float* wa2    = (const float*)d_in[16];
    const float* ba2    = (const float*)d_in[17];

    float* out = (float*)d_out;
    float* w = (float*)d_ws;
    float* SEG_A   = w; w += (size_t)NB * C * HW;
    float* SEG_SIMT= w; w += (size_t)NB * C * HW;   // seg_sim TRANSPOSED [n][pos][ch]; later Tt [n][ch][pos]
    float* SEGS    = w; w += (size_t)NB * NS * HW;
    float* SEGC    = w; w += (size_t)NB * NS * HW;
    float* TBUF    = w; w += (size_t)NB * HW * C;   // T [n][pos][ch]; later X1t [n][ch][pos]
    float* OBUF    = w; w += (size_t)NB * HW * C;   // X2t
    float* BBUF    = w; w += (size_t)NB * HW * HW;
    float* ACCUM   = w; w += (size_t)NB * HW * HW;
    float* ubuf    = w; w += NB * HW;
    float* vbuf    = w; w += NB * HW;
    float* ssbuf   = w; w += NB * HW;
    float* embuf   = w; w += NB * HW;
    float* dcinv   = w; w += NB * HW;
    float* dsinv   = w; w += NB * HW;
    float* dfinv   = w; w += NB * HW;
    float* rowsf   = w; w += NB * HW;
    float* diagrow = w; w += NB * HW;
    float* sqrow   = w; w += NB * HW;
    float* pooled  = w; w += NB * C;
    float* cabuf   = w; w += NB * NS;
    float* scal    = w; w += 16;

    const long long sAdj = (long long)HW * HW;
    const long long sSeg = (long long)C * HW;
    const long long sSgs = (long long)NS * HW;

    for (int it = 0; it < 3; ++it) {
        const float* seg_src = (it == 0) ? seg_in : SEG_A;
        k_conv_sc<<<dim3(NS, NB), 256, 0, stream>>>(seg_src, ws1, bs1, ws11, bs11, SEGS, SEGC);
        k_pooled<<<dim3(C, NB), 256, 0, stream>>>(seg_src, pooled);
        k_ca<<<dim3(NB), 64, 0, stream>>>(pooled, wmlp, bmlp, cabuf);
        k_vecs<<<dim3(4, NB, 4), 256, 0, stream>>>(seg_src, edge, SEGS, cabuf,
                                                   ws2, bs2, ws3, bs3,
                                                   ubuf, vbuf, ssbuf, embuf);
        // B-build (f32, unchanged): B[p,q] = (sigma_T @ sigma) * em[p] * ss[q]
        k_gemm64<1><<<dim3(16, 16, NB), 256, 0, stream>>>(SEGC, sSgs, NS, SEGC, sSgs, HW,
                                                          BBUF, sAdj, HW, NS,
                                                          embuf, HW, ssbuf, HW);
        k_symB<<<dim3(HW, NB), 256, 0, stream>>>(BBUF);
        k_rowsum_cs<<<dim3(HW, NB), 256, 0, stream>>>(BBUF, ubuf, vbuf, dcinv, dsinv);
        k_build_sim<<<dim3(HW, NB), 256, 0, stream>>>(BBUF, ubuf, vbuf, dcinv, dsinv, dfinv);
        k_norm_accum<<<dim3(HW, NB), 256, 0, stream>>>(BBUF, dfinv, ACCUM, it == 0 ? 1 : 0);
        // seg_sim^T = (seg @ sim)^T : NT form, Bsrc = sim (symmetric). MODE 0 -> SEG_SIMT[pos][ch]
        k_mfma2<64, 128, 0><<<dim3(8, 4, NB), 256, 0, stream>>>(
            seg_src, sSeg, HW, BBUF, sAdj, HW, HW,
            SEG_SIMT, sSeg, C, nullptr, nullptr, 0);
        // seg' = relu(wgcn @ seg_sim + bgcn) + seg : NT form, Bsrc = SEG_SIMT. MODE 2
        k_mfma2<64, 128, 2><<<dim3(8, 4, NB), 256, 0, stream>>>(
            wgcn, 0, C, SEG_SIMT, sSeg, C, C,
            SEG_A, sSeg, HW, bgcn, seg_src, sSeg);
    }

    // final adjacency + regularizer (r5-verified)
    k_final_rowsum<<<dim3(HW, NB), 256, 0, stream>>>(ACCUM, dcinv);
    k_final_norm<<<dim3(HW, NB), 256, 0, stream>>>(ACCUM, dcinv, rowsf, diagrow, sqrow);
    k_scal<<<dim3(1), 256, 0, stream>>>(diagrow, sqrow, scal);
    k_reg<<<dim3(NB), 256, 0, stream>>>(rowsf, scal, out + (size_t)NB * C * HW);

    // APPNP, transposed formulation: Yt = 0.5 * Xt @ adj + 0.5 * Tt  (adj symmetric)
    k_appnp_t<<<dim3(HW, NB), 256, 0, stream>>>(seg_in, wa1, ba1, wa2, ba2, TBUF);
    k_transpose<<<dim3(16, 4, NB), 256, 0, stream>>>(TBUF, SEG_SIMT);   // Tt = T^T
    // prop1: X1t(TBUF) = 0.5*Tt@adj + 0.5*Tt
    k_mfma2<64, 128, 3><<<dim3(8, 4, NB), 256, 0, stream>>>(
        SEG_SIMT, sSeg, HW, ACCUM, sAdj, HW, HW,
        TBUF, sSeg, HW, nullptr, SEG_SIMT, sSeg);
    // prop2: X2t(OBUF) = 0.5*X1t@adj + 0.5*Tt
    k_mfma2<64, 128, 3><<<dim3(8, 4, NB), 256, 0, stream>>>(
        TBUF, sSeg, HW, ACCUM, sAdj, HW, HW,
        OBUF, sSeg, HW, nullptr, SEG_SIMT, sSeg);
    // prop3: out[pos][ch] = 0.5*X2t@adj + 0.5*Tt  (MODE 4 writes untransposed)
    k_mfma2<64, 128, 4><<<dim3(8, 4, NB), 256, 0, stream>>>(
        OBUF, sSeg, HW, ACCUM, sAdj, HW, HW,
        out, sSeg, C, nullptr, SEG_SIMT, sSeg);
}

// Round 9
// 778.915 us; speedup vs baseline: 3.6824x; 1.3772x over previous
//
#include <hip/hip_runtime.h>
#include <math.h>

#define NB 8
#define C 256
#define HW 1024
#define NS 64

typedef unsigned short u16;
typedef __attribute__((ext_vector_type(8))) short bf16x8;
typedef __attribute__((ext_vector_type(4))) float f32x4;

__device__ __forceinline__ u16 f2bf(float x) {
    union { float f; unsigned u; } v; v.f = x;
    unsigned r = v.u + 0x7fffu + ((v.u >> 16) & 1u);
    return (u16)(r >> 16);
}
__device__ __forceinline__ float bf2f(u16 h) {
    union { unsigned u; float f; } v; v.u = ((unsigned)h) << 16; return v.f;
}
__device__ __forceinline__ void splitbf(float x, u16& h, u16& l) {
    h = f2bf(x);
    l = f2bf(x - bf2f(h));
}

__device__ __forceinline__ float blockReduceSum(float v, float* s4) {
    #pragma unroll
    for (int o = 32; o; o >>= 1) v += __shfl_down(v, o);
    __syncthreads();
    if ((threadIdx.x & 63) == 0) s4[threadIdx.x >> 6] = v;
    __syncthreads();
    return s4[0] + s4[1] + s4[2] + s4[3];
}

// ================= verified pipeline kernels =================

__global__ void k_conv_sc(const float* __restrict__ seg,
                          const float* __restrict__ ws1, const float* __restrict__ bs1,
                          const float* __restrict__ ws11, const float* __restrict__ bs11,
                          float* __restrict__ seg_s, float* __restrict__ seg_c) {
    int s = blockIdx.x, n = blockIdx.y, tid = threadIdx.x;
    __shared__ float w1[C], w2[C];
    w1[tid] = ws1[s * C + tid];
    w2[tid] = ws11[s * C + tid];
    __syncthreads();
    const float* sb = seg + (size_t)n * C * HW;
    float a0 = 0, a1 = 0, a2 = 0, a3 = 0, b0 = 0, b1 = 0, b2 = 0, b3 = 0;
    for (int c = 0; c < C; ++c) {
        const float* row = sb + (size_t)c * HW;
        float w1c = w1[c], w2c = w2[c];
        float s0 = row[tid], s1 = row[tid + 256], s2 = row[tid + 512], s3 = row[tid + 768];
        a0 += s0 * w1c; a1 += s1 * w1c; a2 += s2 * w1c; a3 += s3 * w1c;
        b0 += s0 * w2c; b1 += s1 * w2c; b2 += s2 * w2c; b3 += s3 * w2c;
    }
    float bias1 = bs1[s], bias2 = bs11[s];
    float* o1 = seg_s + ((size_t)n * NS + s) * HW;
    float* o2 = seg_c + ((size_t)n * NS + s) * HW;
    o1[tid] = a0 + bias1; o1[tid + 256] = a1 + bias1; o1[tid + 512] = a2 + bias1; o1[tid + 768] = a3 + bias1;
    o2[tid] = b0 + bias2; o2[tid + 256] = b1 + bias2; o2[tid + 512] = b2 + bias2; o2[tid + 768] = b3 + bias2;
}

// transpose SEGC [64][1024] -> SEGCT [1024][64] per image
__global__ void k_transpose_sc(const float* __restrict__ in, float* __restrict__ outp) {
    int tc = blockIdx.x, n = blockIdx.y, tid = threadIdx.x;
    int c0 = tc * 64;
    const float* ib = in + (size_t)n * NS * HW;
    float* ob = outp + (size_t)n * NS * HW;
    __shared__ float L[64][65];
    for (int idx = tid; idx < 4096; idx += 256) {
        int r = idx >> 6, c = idx & 63;
        L[r][c] = ib[(size_t)r * HW + c0 + c];
    }
    __syncthreads();
    for (int idx = tid; idx < 4096; idx += 256) {
        int r = idx >> 6, c = idx & 63;
        ob[(size_t)(c0 + r) * 64 + c] = L[c][r];
    }
}

__global__ void k_pooled(const float* __restrict__ seg, float* __restrict__ pooled) {
    int c = blockIdx.x, n = blockIdx.y, tid = threadIdx.x;
    const float* row = seg + ((size_t)n * C + c) * HW;
    float acc = row[tid] + row[tid + 256] + row[tid + 512] + row[tid + 768];
    __shared__ float s4[4];
    float r = blockReduceSum(acc, s4);
    if (tid == 0) pooled[n * C + c] = r * (1.0f / HW);
}

__global__ void k_ca(const float* __restrict__ pooled, const float* __restrict__ wmlp,
                     const float* __restrict__ bmlp, float* __restrict__ ca) {
    int n = blockIdx.x, s = threadIdx.x;
    __shared__ float pl[C];
    for (int i = s; i < C; i += 64) pl[i] = pooled[n * C + i];
    __syncthreads();
    float acc = 0.f;
    for (int c = 0; c < C; ++c) acc += pl[c] * wmlp[s * C + c];
    float r = acc + bmlp[s];
    ca[n * NS + s] = r > 0.f ? r : 0.f;
}

__global__ void k_vecs(const float* __restrict__ seg, const float* __restrict__ edge,
                       const float* __restrict__ seg_s, const float* __restrict__ ca,
                       const float* __restrict__ ws2, const float* __restrict__ bs2,
                       const float* __restrict__ ws3, const float* __restrict__ bs3,
                       float* __restrict__ u, float* __restrict__ vv,
                       float* __restrict__ segss, float* __restrict__ edgemm) {
    int pos = blockIdx.x * 256 + threadIdx.x;
    int n = blockIdx.y, role = blockIdx.z;
    if (role == 0) {
        __shared__ float cs[NS];
        if (threadIdx.x < NS) cs[threadIdx.x] = ca[n * NS + threadIdx.x];
        __syncthreads();
        const float* base = seg_s + (size_t)n * NS * HW + (size_t)pos * NS;
        float acc = 0.f;
        #pragma unroll
        for (int s = 0; s < NS; ++s) acc += base[s] * cs[s];
        u[n * HW + pos] = acc;
    } else if (role == 1) {
        __shared__ float cs[NS];
        if (threadIdx.x < NS) cs[threadIdx.x] = ca[n * NS + threadIdx.x];
        __syncthreads();
        const float* base = seg_s + (size_t)n * NS * HW + pos;
        float acc = 0.f;
        #pragma unroll
        for (int s = 0; s < NS; ++s) acc += cs[s] * base[(size_t)s * HW];
        vv[n * HW + pos] = acc;
    } else if (role == 2) {
        const float* base = seg + (size_t)n * C * HW + pos;
        float m = -3.402823466e38f;
        for (int c = 0; c < C; ++c) m = fmaxf(m, base[(size_t)c * HW]);
        segss[n * HW + pos] = ws2[0] * m + bs2[0];
    } else {
        const float* sb = seg + (size_t)n * C * HW + pos;
        const float* eb = edge + (size_t)n * C * HW + pos;
        float m = -3.402823466e38f;
        for (int c = 0; c < C; ++c) m = fmaxf(m, sb[(size_t)c * HW] * eb[(size_t)c * HW]);
        edgemm[n * HW + pos] = ws3[0] * m + bs3[0];
    }
}

// ===================== fused MFMA B-build + threshold + symmetrize + rowsum =====================
// Block = unordered tile pair (i,j), i<=j, 64x64 tiles.
// raw[p][q] = (sum_s Araw[p][s]*CT[q][s]) * em[p] * ss[q]; thr; sym = 0.5(thr(pq)+thr(qp)).
// Writes both tiles of B, accumulates row sums into dsum (64 atomics/block).
// NT-MFMA with the r8-certified contiguous frag map; split-bf16 (~f32 accurate).
__global__ __launch_bounds__(256) void k_bbuild(
    const float* __restrict__ Araw, const float* __restrict__ CT,
    const float* __restrict__ em, const float* __restrict__ ss,
    float* __restrict__ B, float* __restrict__ dsum) {
    constexpr int LDK = 72;           // padded k-stride (u16), 144B rows
    constexpr int TSZ = 64 * LDK;     // u16 per (hi or lo) tile plane
    __shared__ __align__(16) u16 sm[4 * 2 * TSZ];   // tiles: 0=A_i 1=A_j 2=CT_i 3=CT_j
    int pi = blockIdx.x, n = blockIdx.y, tid = threadIdx.x;
    int i = 0, base = 0;
    while (pi >= base + (16 - i)) { base += 16 - i; ++i; }
    int j = i + (pi - base);
    int i0 = i * 64, j0 = j * 64;
    bool diag = (i == j);
    const float* An = Araw + (size_t)n * NS * HW;
    const float* Cn = CT + (size_t)n * NS * HW;
    const float* emn = em + n * HW;
    const float* ssn = ss + n * HW;
    float* Bn = B + (size_t)n * HW * HW;

    // ---- stage tiles (64 rows x 64 k, f32 -> split bf16) ----
    auto stage = [&](int t, const float* src, int r0) {
        u16* hi = sm + t * 2 * TSZ;
        u16* lo = hi + TSZ;
        #pragma unroll
        for (int p = 0; p < 2; ++p) {
            int e = (p * 256 + tid) * 8;
            int r = e >> 6, k0 = e & 63;
            const float* s = src + (size_t)(r0 + r) * 64 + k0;
            float4 w0 = *(const float4*)s;
            float4 w1 = *(const float4*)(s + 4);
            float xs[8] = {w0.x, w0.y, w0.z, w0.w, w1.x, w1.y, w1.z, w1.w};
            u16 h[8], l[8];
            #pragma unroll
            for (int q = 0; q < 8; ++q) splitbf(xs[q], h[q], l[q]);
            int b = r * LDK + k0;
            *(bf16x8*)(hi + b) = (bf16x8){(short)h[0], (short)h[1], (short)h[2], (short)h[3],
                                          (short)h[4], (short)h[5], (short)h[6], (short)h[7]};
            *(bf16x8*)(lo + b) = (bf16x8){(short)l[0], (short)l[1], (short)l[2], (short)l[3],
                                          (short)l[4], (short)l[5], (short)l[6], (short)l[7]};
        }
    };
    stage(0, An, i0);
    stage(2, Cn, i0);
    if (!diag) { stage(1, An, j0); stage(3, Cn, j0); }
    __syncthreads();

    int lane = tid & 63, wv = tid >> 6;
    int g = lane >> 4;                 // k-group / row-group
    f32x4 acc1[4], acc2[4];
    #pragma unroll
    for (int ni = 0; ni < 4; ++ni) {
        acc1[ni] = (f32x4){0.f, 0.f, 0.f, 0.f};
        acc2[ni] = (f32x4){0.f, 0.f, 0.f, 0.f};
    }

    const u16* AiH = sm + 0 * 2 * TSZ; const u16* AiL = AiH + TSZ;
    const u16* AjH = sm + 1 * 2 * TSZ; const u16* AjL = AjH + TSZ;
    const u16* BiH = sm + 2 * 2 * TSZ; const u16* BiL = BiH + TSZ;
    const u16* BjH = sm + 3 * 2 * TSZ; const u16* BjL = BjH + TSZ;

    #pragma unroll
    for (int kk = 0; kk < 2; ++kk) {
        int kl = kk * 32 + g * 8;
        int arow = wv * 16 + (lane & 15);
        bf16x8 a1h = *(const bf16x8*)(AiH + arow * LDK + kl);
        bf16x8 a1l = *(const bf16x8*)(AiL + arow * LDK + kl);
        bf16x8 a2h, a2l;
        if (!diag) {
            a2h = *(const bf16x8*)(AjH + arow * LDK + kl);
            a2l = *(const bf16x8*)(AjL + arow * LDK + kl);
        }
        #pragma unroll
        for (int ni = 0; ni < 4; ++ni) {
            int brow = ni * 16 + (lane & 15);
            if (diag) {
                bf16x8 bh = *(const bf16x8*)(BiH + brow * LDK + kl);
                bf16x8 bl = *(const bf16x8*)(BiL + brow * LDK + kl);
                acc1[ni] = __builtin_amdgcn_mfma_f32_16x16x32_bf16(a1h, bh, acc1[ni], 0, 0, 0);
                acc1[ni] = __builtin_amdgcn_mfma_f32_16x16x32_bf16(a1h, bl, acc1[ni], 0, 0, 0);
                acc1[ni] = __builtin_amdgcn_mfma_f32_16x16x32_bf16(a1l, bh, acc1[ni], 0, 0, 0);
            } else {
                bf16x8 b1h = *(const bf16x8*)(BjH + brow * LDK + kl);
                bf16x8 b1l = *(const bf16x8*)(BjL + brow * LDK + kl);
                acc1[ni] = __builtin_amdgcn_mfma_f32_16x16x32_bf16(a1h, b1h, acc1[ni], 0, 0, 0);
                acc1[ni] = __builtin_amdgcn_mfma_f32_16x16x32_bf16(a1h, b1l, acc1[ni], 0, 0, 0);
                acc1[ni] = __builtin_amdgcn_mfma_f32_16x16x32_bf16(a1l, b1h, acc1[ni], 0, 0, 0);
                bf16x8 b2h = *(const bf16x8*)(BiH + brow * LDK + kl);
                bf16x8 b2l = *(const bf16x8*)(BiL + brow * LDK + kl);
                acc2[ni] = __builtin_amdgcn_mfma_f32_16x16x32_bf16(a2h, b2h, acc2[ni], 0, 0, 0);
                acc2[ni] = __builtin_amdgcn_mfma_f32_16x16x32_bf16(a2h, b2l, acc2[ni], 0, 0, 0);
                acc2[ni] = __builtin_amdgcn_mfma_f32_16x16x32_bf16(a2l, b2h, acc2[ni], 0, 0, 0);
            }
        }
    }
    __syncthreads();   // done with staged tiles; reuse LDS for exchange

    // ---- threshold + exchange ----
    float* t1 = (float*)sm;            // [64][65]  thr tile (i,j)
    float* t2 = t1 + 64 * 65;          // [64][65]  thr tile (j,i)
    float x[4][4], y[4][4];
    #pragma unroll
    for (int ni = 0; ni < 4; ++ni) {
        int col = ni * 16 + (lane & 15);
        #pragma unroll
        for (int r = 0; r < 4; ++r) {
            int row = wv * 16 + g * 4 + r;     // C/D layout: row=(lane>>4)*4+r
            float v1 = acc1[ni][r] * emn[i0 + row] * ssn[j0 + col];
            v1 = v1 < 0.15f ? 0.f : v1;
            x[ni][r] = v1;
            t1[row * 65 + col] = v1;
            if (!diag) {
                float v2 = acc2[ni][r] * emn[j0 + row] * ssn[i0 + col];
                v2 = v2 < 0.15f ? 0.f : v2;
                y[ni][r] = v2;
                t2[row * 65 + col] = v2;
            }
        }
    }
    __syncthreads();

    // ---- symmetrize, write both tiles, fused row sums ----
    float rs1[4] = {0.f, 0.f, 0.f, 0.f}, rs2[4] = {0.f, 0.f, 0.f, 0.f};
    #pragma unroll
    for (int ni = 0; ni < 4; ++ni) {
        int col = ni * 16 + (lane & 15);
        #pragma unroll
        for (int r = 0; r < 4; ++r) {
            int row = wv * 16 + g * 4 + r;
            float s1 = 0.5f * (x[ni][r] + (diag ? t1[col * 65 + row] : t2[col * 65 + row]));
            Bn[(size_t)(i0 + row) * HW + j0 + col] = s1;
            rs1[r] += s1;
            if (!diag) {
                float s2 = 0.5f * (y[ni][r] + t1[col * 65 + row]);
                Bn[(size_t)(j0 + row) * HW + i0 + col] = s2;
                rs2[r] += s2;
            }
        }
    }
    #pragma unroll
    for (int r = 0; r < 4; ++r) {
        #pragma unroll
        for (int m = 1; m < 16; m <<= 1) {
            rs1[r] += __shfl_xor(rs1[r], m);
            rs2[r] += __shfl_xor(rs2[r], m);
        }
    }
    if ((lane & 15) == 0) {
        #pragma unroll
        for (int r = 0; r < 4; ++r) {
            int row = wv * 16 + g * 4 + r;
            atomicAdd(&dsum[n * HW + i0 + row], rs1[r]);
            if (!diag) atomicAdd(&dsum[n * HW + j0 + row], rs2[r]);
        }
    }
}

// ===================== MFMA split-bf16 NT-GEMM (r8-certified) =====================
template<int BM, int BN, int MODE>
__global__ __launch_bounds__(256) void k_mfma2(
    const float* __restrict__ Af, long long sA, int lda,
    const float* __restrict__ Bf, long long sB, int ldb,
    int K,
    float* __restrict__ Cf, long long sCf, int ldc,
    const float* __restrict__ e1,
    const float* __restrict__ e2, long long se2) {
    constexpr int WM = BM / 32;
    constexpr int WN = BN / 32;
    constexpr int LDK = 72;
    __shared__ __align__(16) u16 sAH[BM * LDK], sAL[BM * LDK];
    __shared__ __align__(16) u16 sBH[BN * LDK], sBL[BN * LDK];
    int n = blockIdx.z;
    int q0 = blockIdx.x * BN, m0 = blockIdx.y * BM;
    int tid = threadIdx.x, lane = tid & 63, wv = tid >> 6;
    int wm = wv >> 1, wn = wv & 1;

    f32x4 acc[WM][WN];
    #pragma unroll
    for (int mi = 0; mi < WM; ++mi)
        #pragma unroll
        for (int ni = 0; ni < WN; ++ni)
            acc[mi][ni] = (f32x4){0.f, 0.f, 0.f, 0.f};

    for (int kt = 0; kt < K; kt += 64) {
        #pragma unroll
        for (int p = 0; p < BM / 32; ++p) {
            int e = (p * 256 + tid) * 8;
            int r = e >> 6, k0 = e & 63;
            const float* src = Af + (size_t)n * sA + (size_t)(m0 + r) * lda + kt + k0;
            float4 w0 = *(const float4*)src;
            float4 w1 = *(const float4*)(src + 4);
            float xs[8] = {w0.x, w0.y, w0.z, w0.w, w1.x, w1.y, w1.z, w1.w};
            u16 h[8], l[8];
            #pragma unroll
            for (int q = 0; q < 8; ++q) splitbf(xs[q], h[q], l[q]);
            int b = r * LDK + k0;
            *(bf16x8*)(sAH + b) = (bf16x8){(short)h[0], (short)h[1], (short)h[2], (short)h[3],
                                           (short)h[4], (short)h[5], (short)h[6], (short)h[7]};
            *(bf16x8*)(sAL + b) = (bf16x8){(short)l[0], (short)l[1], (short)l[2], (short)l[3],
                                           (short)l[4], (short)l[5], (short)l[6], (short)l[7]};
        }
        #pragma unroll
        for (int p = 0; p < BN / 32; ++p) {
            int e = (p * 256 + tid) * 8;
            int c = e >> 6, k0 = e & 63;
            const float* src = Bf + (size_t)n * sB + (size_t)(q0 + c) * ldb + kt + k0;
            float4 w0 = *(const float4*)src;
            float4 w1 = *(const float4*)(src + 4);
            float xs[8] = {w0.x, w0.y, w0.z, w0.w, w1.x, w1.y, w1.z, w1.w};
            u16 h[8], l[8];
            #pragma unroll
            for (int q = 0; q < 8; ++q) splitbf(xs[q], h[q], l[q]);
            int b = c * LDK + k0;
            *(bf16x8*)(sBH + b) = (bf16x8){(short)h[0], (short)h[1], (short)h[2], (short)h[3],
                                           (short)h[4], (short)h[5], (short)h[6], (short)h[7]};
            *(bf16x8*)(sBL + b) = (bf16x8){(short)l[0], (short)l[1], (short)l[2], (short)l[3],
                                           (short)l[4], (short)l[5], (short)l[6], (short)l[7]};
        }
        __syncthreads();
        #pragma unroll
        for (int kk = 0; kk < 2; ++kk) {
            int klocal = kk * 32 + (lane >> 4) * 8;
            bf16x8 aH[WM], aL[WM], bH[WN], bL[WN];
            #pragma unroll
            for (int mi = 0; mi < WM; ++mi) {
                int row = (wm * WM + mi) * 16 + (lane & 15);
                aH[mi] = *(const bf16x8*)(sAH + row * LDK + klocal);
                aL[mi] = *(const bf16x8*)(sAL + row * LDK + klocal);
            }
            #pragma unroll
            for (int ni = 0; ni < WN; ++ni) {
                int col = (wn * WN + ni) * 16 + (lane & 15);
                bH[ni] = *(const bf16x8*)(sBH + col * LDK + klocal);
                bL[ni] = *(const bf16x8*)(sBL + col * LDK + klocal);
            }
            #pragma unroll
            for (int mi = 0; mi < WM; ++mi)
                #pragma unroll
                for (int ni = 0; ni < WN; ++ni) {
                    acc[mi][ni] = __builtin_amdgcn_mfma_f32_16x16x32_bf16(aH[mi], bH[ni], acc[mi][ni], 0, 0, 0);
                    acc[mi][ni] = __builtin_amdgcn_mfma_f32_16x16x32_bf16(aH[mi], bL[ni], acc[mi][ni], 0, 0, 0);
                    acc[mi][ni] = __builtin_amdgcn_mfma_f32_16x16x32_bf16(aL[mi], bH[ni], acc[mi][ni], 0, 0, 0);
                }
        }
        __syncthreads();
    }

    #pragma unroll
    for (int mi = 0; mi < WM; ++mi) {
        #pragma unroll
        for (int ni = 0; ni < WN; ++ni) {
            int col = q0 + (wn * WN + ni) * 16 + (lane & 15);
            int rowb = m0 + (wm * WM + mi) * 16 + (lane >> 4) * 4;
            #pragma unroll
            for (int r = 0; r < 4; ++r) {
                int row = rowb + r;
                float val = acc[mi][ni][r];
                if (MODE == 0) {
                    Cf[(size_t)n * sCf + (size_t)col * ldc + row] = val;
                } else if (MODE == 2) {
                    val = fmaxf(val + e1[row], 0.f) + e2[(size_t)n * se2 + (size_t)row * ldc + col];
                    Cf[(size_t)n * sCf + (size_t)row * ldc + col] = val;
                } else if (MODE == 3) {
                    val = 0.5f * val + 0.5f * e2[(size_t)n * se2 + (size_t)row * ldc + col];
                    Cf[(size_t)n * sCf + (size_t)row * ldc + col] = val;
                } else {  // MODE 4
                    val = 0.5f * val + 0.5f * e2[(size_t)n * se2 + (size_t)row * HW + col];
                    Cf[(size_t)n * sCf + (size_t)col * ldc + row] = val;
                }
            }
        }
    }
}

// transpose [1024 x 256] -> [256 x 1024] per image (for APPNP Tt)
__global__ void k_transpose(const float* __restrict__ in, float* __restrict__ outp) {
    int ti = blockIdx.x, tj = blockIdx.y, n = blockIdx.z, tid = threadIdx.x;
    int i0 = ti * 64, j0 = tj * 64;
    const float* ib = in + (size_t)n * HW * C;
    float* ob = outp + (size_t)n * C * HW;
    __shared__ float L[64][65];
    for (int idx = tid; idx < 4096; idx += 256) {
        int r = idx >> 6, c = idx & 63;
        L[r][c] = ib[(size_t)(i0 + r) * C + (j0 + c)];
    }
    __syncthreads();
    for (int idx = tid; idx < 4096; idx += 256) {
        int r = idx >> 6, c = idx & 63;
        ob[(size_t)(j0 + r) * HW + (i0 + c)] = L[c][r];
    }
}

// ---------------- adjacency/reduction chain ----------------
__global__ void k_dinv(const float* __restrict__ u, const float* __restrict__ vv,
                       const float* __restrict__ dsum,
                       float* __restrict__ dcinv, float* __restrict__ dsinv) {
    int p = blockIdx.x, n = blockIdx.y, tid = threadIdx.x;
    const float* un = u + n * HW;
    const float* vn = vv + n * HW;
    float up = un[p], vp = vn[p];
    float acc_c = 0.f;
    for (int q = tid; q < HW; q += 256) {
        float x = up * vn[q]; x = x < 0.15f ? 0.f : x;
        float y = un[q] * vp; y = y < 0.15f ? 0.f : y;
        acc_c += 0.5f * (x + y);
    }
    __shared__ float s4[4];
    acc_c = blockReduceSum(acc_c, s4);
    if (tid == 0) {
        dcinv[n * HW + p] = 1.0f / sqrtf(acc_c + 1.0f);
        dsinv[n * HW + p] = 1.0f / sqrtf(dsum[n * HW + p] + 1.0f);
    }
}

__global__ void k_build_sim(float* __restrict__ B, const float* __restrict__ u,
                            const float* __restrict__ vv, const float* __restrict__ dcinv,
                            const float* __restrict__ dsinv, float* __restrict__ dfinv) {
    int p = blockIdx.x, n = blockIdx.y, tid = threadIdx.x;
    float* Bb = B + (size_t)n * HW * HW + (size_t)p * HW;
    const float* un = u + n * HW;
    const float* vn = vv + n * HW;
    const float* dci = dcinv + n * HW;
    const float* dsi = dsinv + n * HW;
    float up = un[p], vp = vn[p], dcp = dci[p], dsp = dsi[p];
    float acc = 0.f;
    for (int q = tid; q < HW; q += 256) {
        float x = up * vn[q]; x = x < 0.15f ? 0.f : x;
        float y = un[q] * vp; y = y < 0.15f ? 0.f : y;
        float delta = (q == p) ? 1.0f : 0.0f;
        float val = (0.5f * (x + y) + delta) * dcp * dci[q] + (Bb[q] + delta) * dsp * dsi[q];
        Bb[q] = val;
        acc += val;
    }
    __shared__ float s4[4];
    acc = blockReduceSum(acc, s4);
    if (tid == 0) dfinv[n * HW + p] = 1.0f / sqrtf(acc + 1.0f);
}

__global__ void k_norm_accum(float* __restrict__ B, const float* __restrict__ dfinv,
                             float* __restrict__ ACC, int first) {
    int p = blockIdx.x, n = blockIdx.y, tid = threadIdx.x;
    float* Bb = B + (size_t)n * HW * HW + (size_t)p * HW;
    float* Ab = ACC + (size_t)n * HW * HW + (size_t)p * HW;
    const float* df = dfinv + n * HW;
    float dfp = df[p];
    for (int q = tid; q < HW; q += 256) {
        float val = (Bb[q] + ((q == p) ? 1.f : 0.f)) * dfp * df[q];
        Bb[q] = val;
        Ab[q] = first ? val : (Ab[q] + val);
    }
}

__global__ void k_final_rowsum(const float* __restrict__ ACC, float* __restrict__ dinv) {
    int p = blockIdx.x, n = blockIdx.y, tid = threadIdx.x;
    const float* Ab = ACC + (size_t)n * HW * HW + (size_t)p * HW;
    float acc = 0.f;
    for (int q = tid; q < HW; q += 256) acc += Ab[q];
    __shared__ float s4[4];
    acc = blockReduceSum(acc, s4);
    if (tid == 0) dinv[n * HW + p] = 1.0f / sqrtf(acc * (1.0f / 3.0f) + 1.0f);
}

__global__ void k_final_norm(float* __restrict__ ACC, const float* __restrict__ dinv,
                             float* __restrict__ rowsf, float* __restrict__ diagrow,
                             float* __restrict__ sqrow) {
    int p = blockIdx.x, n = blockIdx.y, tid = threadIdx.x;
    float* Ab = ACC + (size_t)n * HW * HW + (size_t)p * HW;
    const float* di = dinv + n * HW;
    float dp = di[p];
    float accr = 0.f, accsq = 0.f, accd = 0.f;
    for (int q = tid; q < HW; q += 256) {
        float val = (Ab[q] * (1.0f / 3.0f) + ((q == p) ? 1.f : 0.f)) * dp * di[q];
        Ab[q] = val;
        accr += val;
        accsq += val * val;
        if (q == p) accd = val;
    }
    __shared__ float s4[4];
    accr = blockReduceSum(accr, s4);
    accsq = blockReduceSum(accsq, s4);
    accd = blockReduceSum(accd, s4);
    if (tid == 0) {
        rowsf[n * HW + p] = accr;
        sqrow[n * HW + p] = accsq;
        diagrow[n * HW + p] = accd;
    }
}

__global__ void k_scal(const float* __restrict__ diagrow, const float* __restrict__ sqrow,
                       float* __restrict__ scal) {
    int tid = threadIdx.x;
    float a = 0.f, b = 0.f;
    for (int i = tid; i < NB * HW; i += 256) { a += diagrow[i]; b += sqrow[i]; }
    __shared__ float s4[4];
    a = blockReduceSum(a, s4);
    b = blockReduceSum(b, s4);
    if (tid == 0) { scal[0] = a; scal[1] = b; }
}

__global__ void k_reg(const float* __restrict__ rowsf, const float* __restrict__ scal,
                      float* __restrict__ outreg) {
    int n = blockIdx.x, tid = threadIdx.x;
    float acc = 0.f;
    for (int p = tid; p < HW; p += 256) acc += logf(rowsf[n * HW + p]);
    __shared__ float s4[4];
    acc = blockReduceSum(acc, s4);
    if (tid == 0) {
        float f = -0.1f * acc / 1024.0f + 0.1f * sqrtf(scal[1]) / 1048576.0f;
        outreg[n] = 0.1f * scal[0] + f;
    }
}

__global__ void k_appnp_t(const float* __restrict__ ori, const float* __restrict__ wa1,
                          const float* __restrict__ ba1, const float* __restrict__ wa2,
                          const float* __restrict__ ba2, float* __restrict__ T) {
    int p = blockIdx.x, n = blockIdx.y, tid = threadIdx.x;
    const float* x = ori + (size_t)n * C * HW + (size_t)p * C;
    float xv = x[tid];
    __shared__ float s4[4];
    __shared__ float h[3];
    float d0 = blockReduceSum(xv * wa1[0 * C + tid], s4);
    float d1 = blockReduceSum(xv * wa1[1 * C + tid], s4);
    float d2 = blockReduceSum(xv * wa1[2 * C + tid], s4);
    if (tid == 0) {
        h[0] = fmaxf(d0 + ba1[0], 0.f);
        h[1] = fmaxf(d1 + ba1[1], 0.f);
        h[2] = fmaxf(d2 + ba1[2], 0.f);
    }
    __syncthreads();
    float t = h[0] * wa2[tid * 3 + 0] + h[1] * wa2[tid * 3 + 1] + h[2] * wa2[tid * 3 + 2] + ba2[tid];
    T[(size_t)n * HW * C + (size_t)p * C + tid] = fmaxf(t, 0.f);
}

// =====================================================================================
extern "C" void kernel_launch(void* const* d_in, const int* in_sizes, int n_in,
                              void* d_out, int out_size, void* d_ws, size_t ws_size,
                              hipStream_t stream) {
    const float* seg_in = (const float*)d_in[0];
    const float* edge   = (const float*)d_in[1];
    const float* ws1    = (const float*)d_in[2];
    const float* bs1    = (const float*)d_in[3];
    const float* ws11   = (const float*)d_in[4];
    const float* bs11   = (const float*)d_in[5];
    const float* ws2    = (const float*)d_in[6];
    const float* bs2    = (const float*)d_in[7];
    const float* ws3    = (const float*)d_in[8];
    const float* bs3    = (const float*)d_in[9];
    const float* wmlp   = (const float*)d_in[10];
    const float* bmlp   = (const float*)d_in[11];
    const float* wgcn   = (const float*)d_in[12];
    const float* bgcn   = (const float*)d_in[13];
    const float* wa1    = (const float*)d_in[14];
    const float* ba1    = (const float*)d_in[15];
    const float* wa2    = (const float*)d_in[16];
    const float* ba2    = (const float*)d_in[17];

    float* out = (float*)d_out;
    float* w = (float*)d_ws;
    float* SEG_A   = w; w += (size_t)NB * C * HW;
    float* SEG_SIMT= w; w += (size_t)NB * C * HW;
    float* SEGS    = w; w += (size_t)NB * NS * HW;
    float* SEGC    = w; w += (size_t)NB * NS * HW;
    float* SEGCT   = w; w += (size_t)NB * NS * HW;
    float* TBUF    = w; w += (size_t)NB * HW * C;
    float* OBUF    = w; w += (size_t)NB * HW * C;
    float* BBUF    = w; w += (size_t)NB * HW * HW;
    float* ACCUM   = w; w += (size_t)NB * HW * HW;
    float* ubuf    = w; w += NB * HW;
    float* vbuf    = w; w += NB * HW;
    float* ssbuf   = w; w += NB * HW;
    float* embuf   = w; w += NB * HW;
    float* dsum    = w; w += NB * HW;
    float* dcinv   = w; w += NB * HW;
    float* dsinv   = w; w += NB * HW;
    float* dfinv   = w; w += NB * HW;
    float* rowsf   = w; w += NB * HW;
    float* diagrow = w; w += NB * HW;
    float* sqrow   = w; w += NB * HW;
    float* pooled  = w; w += NB * C;
    float* cabuf   = w; w += NB * NS;
    float* scal    = w; w += 16;

    const long long sAdj = (long long)HW * HW;
    const long long sSeg = (long long)C * HW;

    for (int it = 0; it < 3; ++it) {
        const float* seg_src = (it == 0) ? seg_in : SEG_A;
        k_conv_sc<<<dim3(NS, NB), 256, 0, stream>>>(seg_src, ws1, bs1, ws11, bs11, SEGS, SEGC);
        k_transpose_sc<<<dim3(16, NB), 256, 0, stream>>>(SEGC, SEGCT);
        k_pooled<<<dim3(C, NB), 256, 0, stream>>>(seg_src, pooled);
        k_ca<<<dim3(NB), 64, 0, stream>>>(pooled, wmlp, bmlp, cabuf);
        k_vecs<<<dim3(4, NB, 4), 256, 0, stream>>>(seg_src, edge, SEGS, cabuf,
                                                   ws2, bs2, ws3, bs3,
                                                   ubuf, vbuf, ssbuf, embuf);
        hipMemsetAsync(dsum, 0, (size_t)NB * HW * sizeof(float), stream);
        // fused B-build + threshold + symmetrize + rowsum
        k_bbuild<<<dim3(136, NB), 256, 0, stream>>>(SEGC, SEGCT, embuf, ssbuf, BBUF, dsum);
        k_dinv<<<dim3(HW, NB), 256, 0, stream>>>(ubuf, vbuf, dsum, dcinv, dsinv);
        k_build_sim<<<dim3(HW, NB), 256, 0, stream>>>(BBUF, ubuf, vbuf, dcinv, dsinv, dfinv);
        k_norm_accum<<<dim3(HW, NB), 256, 0, stream>>>(BBUF, dfinv, ACCUM, it == 0 ? 1 : 0);
        // seg_sim^T = (seg @ sim)^T : NT, Bsrc = sim (symmetric), MODE 0 -> [pos][ch]
        k_mfma2<64, 128, 0><<<dim3(8, 4, NB), 256, 0, stream>>>(
            seg_src, sSeg, HW, BBUF, sAdj, HW, HW,
            SEG_SIMT, sSeg, C, nullptr, nullptr, 0);
        // seg' = relu(wgcn @ seg_sim + bgcn) + seg : NT, Bsrc = SEG_SIMT, MODE 2
        k_mfma2<64, 128, 2><<<dim3(8, 4, NB), 256, 0, stream>>>(
            wgcn, 0, C, SEG_SIMT, sSeg, C, C,
            SEG_A, sSeg, HW, bgcn, seg_src, sSeg);
    }

    // final adjacency + regularizer
    k_final_rowsum<<<dim3(HW, NB), 256, 0, stream>>>(ACCUM, dcinv);
    k_final_norm<<<dim3(HW, NB), 256, 0, stream>>>(ACCUM, dcinv, rowsf, diagrow, sqrow);
    k_scal<<<dim3(1), 256, 0, stream>>>(diagrow, sqrow, scal);
    k_reg<<<dim3(NB), 256, 0, stream>>>(rowsf, scal, out + (size_t)NB * C * HW);

    // APPNP, transposed formulation: Yt = 0.5 * Xt @ adj + 0.5 * Tt  (adj symmetric)
    k_appnp_t<<<dim3(HW, NB), 256, 0, stream>>>(seg_in, wa1, ba1, wa2, ba2, TBUF);
    k_transpose<<<dim3(16, 4, NB), 256, 0, stream>>>(TBUF, SEG_SIMT);   // Tt
    k_mfma2<64, 128, 3><<<dim3(8, 4, NB), 256, 0, stream>>>(
        SEG_SIMT, sSeg, HW, ACCUM, sAdj, HW, HW,
        TBUF, sSeg, HW, nullptr, SEG_SIMT, sSeg);
    k_mfma2<64, 128, 3><<<dim3(8, 4, NB), 256, 0, stream>>>(
        TBUF, sSeg, HW, ACCUM, sAdj, HW, HW,
        OBUF, sSeg, HW, nullptr, SEG_SIMT, sSeg);
    k_mfma2<64, 128, 4><<<dim3(8, 4, NB), 256, 0, stream>>>(
        OBUF, sSeg, HW, ACCUM, sAdj, HW, HW,
        out, sSeg, C, nullptr, SEG_SIMT, sSeg);
}

// Round 10
// 693.636 us; speedup vs baseline: 4.1352x; 1.1229x over previous
//
#include <hip/hip_runtime.h>
#include <math.h>

#define NB 8
#define C 256
#define HW 1024
#define NS 64

typedef unsigned short u16;
typedef __attribute__((ext_vector_type(8))) short bf16x8;
typedef __attribute__((ext_vector_type(4))) float f32x4;

__device__ __forceinline__ u16 f2bf(float x) {
    union { float f; unsigned u; } v; v.f = x;
    unsigned r = v.u + 0x7fffu + ((v.u >> 16) & 1u);
    return (u16)(r >> 16);
}
__device__ __forceinline__ float bf2f(u16 h) {
    union { unsigned u; float f; } v; v.u = ((unsigned)h) << 16; return v.f;
}
__device__ __forceinline__ void splitbf(float x, u16& h, u16& l) {
    h = f2bf(x);
    l = f2bf(x - bf2f(h));
}

__device__ __forceinline__ float blockReduceSum(float v, float* s4) {
    #pragma unroll
    for (int o = 32; o; o >>= 1) v += __shfl_down(v, o);
    __syncthreads();
    if ((threadIdx.x & 63) == 0) s4[threadIdx.x >> 6] = v;
    __syncthreads();
    return s4[0] + s4[1] + s4[2] + s4[3];
}

// ---------------- once-per-launch: concat conv weights/biases ----------------
__global__ void k_prepw(const float* __restrict__ ws1, const float* __restrict__ bs1,
                        const float* __restrict__ ws11, const float* __restrict__ bs11,
                        float* __restrict__ WCAT, float* __restrict__ BCAT) {
    int tid = blockIdx.x * 256 + threadIdx.x;
    if (tid < 64 * C) {
        WCAT[tid] = ws1[tid];
        WCAT[64 * C + tid] = ws11[tid];
    }
    if (tid < 64) { BCAT[tid] = bs1[tid]; BCAT[64 + tid] = bs11[tid]; }
}

// ---------------- generic 64x64-tile transpose: in[R][Cin] -> out[Cin][R] ----------------
template<int R, int CIN>
__global__ void k_transp(const float* __restrict__ in, long long sIn,
                         float* __restrict__ outp, long long sOut) {
    int ti = blockIdx.x, tj = blockIdx.y, n = blockIdx.z, tid = threadIdx.x;
    int i0 = ti * 64, j0 = tj * 64;   // i over R rows, j over CIN cols
    const float* ib = in + (size_t)n * sIn;
    float* ob = outp + (size_t)n * sOut;
    __shared__ float L[64][65];
    for (int idx = tid; idx < 4096; idx += 256) {
        int r = idx >> 6, c = idx & 63;
        L[r][c] = ib[(size_t)(i0 + r) * CIN + (j0 + c)];
    }
    __syncthreads();
    for (int idx = tid; idx < 4096; idx += 256) {
        int r = idx >> 6, c = idx & 63;
        ob[(size_t)(j0 + r) * R + (i0 + c)] = L[c][r];
    }
}

__global__ void k_pooled(const float* __restrict__ seg, float* __restrict__ pooled) {
    int c = blockIdx.x, n = blockIdx.y, tid = threadIdx.x;
    const float* row = seg + ((size_t)n * C + c) * HW;
    float acc = row[tid] + row[tid + 256] + row[tid + 512] + row[tid + 768];
    __shared__ float s4[4];
    float r = blockReduceSum(acc, s4);
    if (tid == 0) pooled[n * C + c] = r * (1.0f / HW);
}

__global__ void k_ca(const float* __restrict__ pooled, const float* __restrict__ wmlp,
                     const float* __restrict__ bmlp, float* __restrict__ ca) {
    int n = blockIdx.x, s = threadIdx.x;
    __shared__ float pl[C];
    for (int i = s; i < C; i += 64) pl[i] = pooled[n * C + i];
    __syncthreads();
    float acc = 0.f;
    for (int c = 0; c < C; ++c) acc += pl[c] * wmlp[s * C + c];
    float r = acc + bmlp[s];
    ca[n * NS + s] = r > 0.f ? r : 0.f;
}

// ---------------- chunked channel maxes (replaces k_vecs roles 2/3) ----------------
__global__ void k_maxes(const float* __restrict__ seg, const float* __restrict__ edge,
                        float* __restrict__ smax, float* __restrict__ emax) {
    int pos = blockIdx.x * 256 + threadIdx.x;
    int n = blockIdx.y, ch = blockIdx.z;
    const float* sb = seg + (size_t)n * C * HW + (size_t)(ch * 32) * HW + pos;
    const float* eb = edge + (size_t)n * C * HW + (size_t)(ch * 32) * HW + pos;
    float ms = -3.402823466e38f, me = -3.402823466e38f;
    #pragma unroll 8
    for (int c = 0; c < 32; ++c) {
        float s = sb[(size_t)c * HW];
        ms = fmaxf(ms, s);
        me = fmaxf(me, s * eb[(size_t)c * HW]);
    }
    smax[((size_t)ch * NB + n) * HW + pos] = ms;
    emax[((size_t)ch * NB + n) * HW + pos] = me;
}

__global__ void k_maxfin(const float* __restrict__ smax, const float* __restrict__ emax,
                         const float* __restrict__ ws2, const float* __restrict__ bs2,
                         const float* __restrict__ ws3, const float* __restrict__ bs3,
                         float* __restrict__ segss, float* __restrict__ edgemm) {
    int pos = blockIdx.x * 256 + threadIdx.x;
    int n = blockIdx.y;
    float ms = -3.402823466e38f, me = -3.402823466e38f;
    #pragma unroll
    for (int ch = 0; ch < 8; ++ch) {
        ms = fmaxf(ms, smax[((size_t)ch * NB + n) * HW + pos]);
        me = fmaxf(me, emax[((size_t)ch * NB + n) * HW + pos]);
    }
    segss[n * HW + pos] = ws2[0] * ms + bs2[0];
    edgemm[n * HW + pos] = ws3[0] * me + bs3[0];
}

// ---------------- u, v (replaces k_vecs roles 0/1); segs = SEGSC rows 0..63 ----------------
__global__ void k_uv(const float* __restrict__ segsc, const float* __restrict__ ca,
                     float* __restrict__ u, float* __restrict__ vv) {
    int pos = blockIdx.x * 256 + threadIdx.x;
    int n = blockIdx.y, role = blockIdx.z;
    const float* flat = segsc + (size_t)n * 128 * HW;   // seg_s flat [64*1024]
    __shared__ float cs[NS];
    if (threadIdx.x < NS) cs[threadIdx.x] = ca[n * NS + threadIdx.x];
    __syncthreads();
    if (role == 0) {        // u[p] = dot(flat[p*64 .. +63], ca)   (raw view)
        const float* base = flat + (size_t)pos * NS;
        float acc = 0.f;
        #pragma unroll
        for (int s = 0; s < NS; ++s) acc += base[s] * cs[s];
        u[n * HW + pos] = acc;
    } else {                // v[q] = sum_s ca[s]*segs[s][q]
        float acc = 0.f;
        #pragma unroll
        for (int s = 0; s < NS; ++s) acc += cs[s] * flat[(size_t)s * HW + pos];
        vv[n * HW + pos] = acc;
    }
}

// ===================== fused MFMA B-build + threshold + symmetrize + rowsum =====================
__global__ __launch_bounds__(256) void k_bbuild(
    const float* __restrict__ Aflat, long long sA,
    const float* __restrict__ CT,
    const float* __restrict__ em, const float* __restrict__ ss,
    float* __restrict__ B, float* __restrict__ dsum) {
    constexpr int LDK = 72;
    constexpr int TSZ = 64 * LDK;
    __shared__ __align__(16) u16 sm[4 * 2 * TSZ];
    int pi = blockIdx.x, n = blockIdx.y, tid = threadIdx.x;
    int i = 0, base = 0;
    while (pi >= base + (16 - i)) { base += 16 - i; ++i; }
    int j = i + (pi - base);
    int i0 = i * 64, j0 = j * 64;
    bool diag = (i == j);
    const float* An = Aflat + (size_t)n * sA;
    const float* Cn = CT + (size_t)n * NS * HW;
    const float* emn = em + n * HW;
    const float* ssn = ss + n * HW;
    float* Bn = B + (size_t)n * HW * HW;

    auto stage = [&](int t, const float* src, int r0) {
        u16* hi = sm + t * 2 * TSZ;
        u16* lo = hi + TSZ;
        #pragma unroll
        for (int p = 0; p < 2; ++p) {
            int e = (p * 256 + tid) * 8;
            int r = e >> 6, k0 = e & 63;
            const float* s = src + (size_t)(r0 + r) * 64 + k0;
            float4 w0 = *(const float4*)s;
            float4 w1 = *(const float4*)(s + 4);
            float xs[8] = {w0.x, w0.y, w0.z, w0.w, w1.x, w1.y, w1.z, w1.w};
            u16 h[8], l[8];
            #pragma unroll
            for (int q = 0; q < 8; ++q) splitbf(xs[q], h[q], l[q]);
            int b = r * LDK + k0;
            *(bf16x8*)(hi + b) = (bf16x8){(short)h[0], (short)h[1], (short)h[2], (short)h[3],
                                          (short)h[4], (short)h[5], (short)h[6], (short)h[7]};
            *(bf16x8*)(lo + b) = (bf16x8){(short)l[0], (short)l[1], (short)l[2], (short)l[3],
                                          (short)l[4], (short)l[5], (short)l[6], (short)l[7]};
        }
    };
    stage(0, An, i0);
    stage(2, Cn, i0);
    if (!diag) { stage(1, An, j0); stage(3, Cn, j0); }
    __syncthreads();

    int lane = tid & 63, wv = tid >> 6;
    int g = lane >> 4;
    f32x4 acc1[4], acc2[4];
    #pragma unroll
    for (int ni = 0; ni < 4; ++ni) {
        acc1[ni] = (f32x4){0.f, 0.f, 0.f, 0.f};
        acc2[ni] = (f32x4){0.f, 0.f, 0.f, 0.f};
    }

    const u16* AiH = sm + 0 * 2 * TSZ; const u16* AiL = AiH + TSZ;
    const u16* AjH = sm + 1 * 2 * TSZ; const u16* AjL = AjH + TSZ;
    const u16* BiH = sm + 2 * 2 * TSZ; const u16* BiL = BiH + TSZ;
    const u16* BjH = sm + 3 * 2 * TSZ; const u16* BjL = BjH + TSZ;

    #pragma unroll
    for (int kk = 0; kk < 2; ++kk) {
        int kl = kk * 32 + g * 8;
        int arow = wv * 16 + (lane & 15);
        bf16x8 a1h = *(const bf16x8*)(AiH + arow * LDK + kl);
        bf16x8 a1l = *(const bf16x8*)(AiL + arow * LDK + kl);
        bf16x8 a2h, a2l;
        if (!diag) {
            a2h = *(const bf16x8*)(AjH + arow * LDK + kl);
            a2l = *(const bf16x8*)(AjL + arow * LDK + kl);
        }
        #pragma unroll
        for (int ni = 0; ni < 4; ++ni) {
            int brow = ni * 16 + (lane & 15);
            if (diag) {
                bf16x8 bh = *(const bf16x8*)(BiH + brow * LDK + kl);
                bf16x8 bl = *(const bf16x8*)(BiL + brow * LDK + kl);
                acc1[ni] = __builtin_amdgcn_mfma_f32_16x16x32_bf16(a1h, bh, acc1[ni], 0, 0, 0);
                acc1[ni] = __builtin_amdgcn_mfma_f32_16x16x32_bf16(a1h, bl, acc1[ni], 0, 0, 0);
                acc1[ni] = __builtin_amdgcn_mfma_f32_16x16x32_bf16(a1l, bh, acc1[ni], 0, 0, 0);
            } else {
                bf16x8 b1h = *(const bf16x8*)(BjH + brow * LDK + kl);
                bf16x8 b1l = *(const bf16x8*)(BjL + brow * LDK + kl);
                acc1[ni] = __builtin_amdgcn_mfma_f32_16x16x32_bf16(a1h, b1h, acc1[ni], 0, 0, 0);
                acc1[ni] = __builtin_amdgcn_mfma_f32_16x16x32_bf16(a1h, b1l, acc1[ni], 0, 0, 0);
                acc1[ni] = __builtin_amdgcn_mfma_f32_16x16x32_bf16(a1l, b1h, acc1[ni], 0, 0, 0);
                bf16x8 b2h = *(const bf16x8*)(BiH + brow * LDK + kl);
                bf16x8 b2l = *(const bf16x8*)(BiL + brow * LDK + kl);
                acc2[ni] = __builtin_amdgcn_mfma_f32_16x16x32_bf16(a2h, b2h, acc2[ni], 0, 0, 0);
                acc2[ni] = __builtin_amdgcn_mfma_f32_16x16x32_bf16(a2h, b2l, acc2[ni], 0, 0, 0);
                acc2[ni] = __builtin_amdgcn_mfma_f32_16x16x32_bf16(a2l, b2h, acc2[ni], 0, 0, 0);
            }
        }
    }
    __syncthreads();

    float* t1 = (float*)sm;
    float* t2 = t1 + 64 * 65;
    float x[4][4], y[4][4];
    #pragma unroll
    for (int ni = 0; ni < 4; ++ni) {
        int col = ni * 16 + (lane & 15);
        #pragma unroll
        for (int r = 0; r < 4; ++r) {
            int row = wv * 16 + g * 4 + r;
            float v1 = acc1[ni][r] * emn[i0 + row] * ssn[j0 + col];
            v1 = v1 < 0.15f ? 0.f : v1;
            x[ni][r] = v1;
            t1[row * 65 + col] = v1;
            if (!diag) {
                float v2 = acc2[ni][r] * emn[j0 + row] * ssn[i0 + col];
                v2 = v2 < 0.15f ? 0.f : v2;
                y[ni][r] = v2;
                t2[row * 65 + col] = v2;
            }
        }
    }
    __syncthreads();

    float rs1[4] = {0.f, 0.f, 0.f, 0.f}, rs2[4] = {0.f, 0.f, 0.f, 0.f};
    #pragma unroll
    for (int ni = 0; ni < 4; ++ni) {
        int col = ni * 16 + (lane & 15);
        #pragma unroll
        for (int r = 0; r < 4; ++r) {
            int row = wv * 16 + g * 4 + r;
            float s1 = 0.5f * (x[ni][r] + (diag ? t1[col * 65 + row] : t2[col * 65 + row]));
            Bn[(size_t)(i0 + row) * HW + j0 + col] = s1;
            rs1[r] += s1;
            if (!diag) {
                float s2 = 0.5f * (y[ni][r] + t1[col * 65 + row]);
                Bn[(size_t)(j0 + row) * HW + i0 + col] = s2;
                rs2[r] += s2;
            }
        }
    }
    #pragma unroll
    for (int r = 0; r < 4; ++r) {
        #pragma unroll
        for (int m = 1; m < 16; m <<= 1) {
            rs1[r] += __shfl_xor(rs1[r], m);
            rs2[r] += __shfl_xor(rs2[r], m);
        }
    }
    if ((lane & 15) == 0) {
        #pragma unroll
        for (int r = 0; r < 4; ++r) {
            int row = wv * 16 + g * 4 + r;
            atomicAdd(&dsum[n * HW + i0 + row], rs1[r]);
            if (!diag) atomicAdd(&dsum[n * HW + j0 + row], rs2[r]);
        }
    }
}

// ===================== MFMA split-bf16 NT-GEMM (certified) =====================
// MODE 0: Ct[col*ldc+row] = acc
// MODE 2: C[row*ldc+col] = relu(acc + e1[row]) + e2[n][row*ldc+col]
// MODE 3: C[row*ldc+col] = 0.5*acc + 0.5*e2[n][row*ldc+col]
// MODE 4: Ct[col*ldc+row] = 0.5*acc + 0.5*e2[n][row*HW+col]
// MODE 5: C[row*ldc+col] = acc + e1[row]                       (conv + bias)
template<int BM, int BN, int MODE>
__global__ __launch_bounds__(256) void k_mfma2(
    const float* __restrict__ Af, long long sA, int lda,
    const float* __restrict__ Bf, long long sB, int ldb,
    int K,
    float* __restrict__ Cf, long long sCf, int ldc,
    const float* __restrict__ e1,
    const float* __restrict__ e2, long long se2) {
    constexpr int WM = BM / 32;
    constexpr int WN = BN / 32;
    constexpr int LDK = 72;
    __shared__ __align__(16) u16 sAH[BM * LDK], sAL[BM * LDK];
    __shared__ __align__(16) u16 sBH[BN * LDK], sBL[BN * LDK];
    int n = blockIdx.z;
    int q0 = blockIdx.x * BN, m0 = blockIdx.y * BM;
    int tid = threadIdx.x, lane = tid & 63, wv = tid >> 6;
    int wm = wv >> 1, wn = wv & 1;

    f32x4 acc[WM][WN];
    #pragma unroll
    for (int mi = 0; mi < WM; ++mi)
        #pragma unroll
        for (int ni = 0; ni < WN; ++ni)
            acc[mi][ni] = (f32x4){0.f, 0.f, 0.f, 0.f};

    for (int kt = 0; kt < K; kt += 64) {
        #pragma unroll
        for (int p = 0; p < BM / 32; ++p) {
            int e = (p * 256 + tid) * 8;
            int r = e >> 6, k0 = e & 63;
            const float* src = Af + (size_t)n * sA + (size_t)(m0 + r) * lda + kt + k0;
            float4 w0 = *(const float4*)src;
            float4 w1 = *(const float4*)(src + 4);
            float xs[8] = {w0.x, w0.y, w0.z, w0.w, w1.x, w1.y, w1.z, w1.w};
            u16 h[8], l[8];
            #pragma unroll
            for (int q = 0; q < 8; ++q) splitbf(xs[q], h[q], l[q]);
            int b = r * LDK + k0;
            *(bf16x8*)(sAH + b) = (bf16x8){(short)h[0], (short)h[1], (short)h[2], (short)h[3],
                                           (short)h[4], (short)h[5], (short)h[6], (short)h[7]};
            *(bf16x8*)(sAL + b) = (bf16x8){(short)l[0], (short)l[1], (short)l[2], (short)l[3],
                                           (short)l[4], (short)l[5], (short)l[6], (short)l[7]};
        }
        #pragma unroll
        for (int p = 0; p < BN / 32; ++p) {
            int e = (p * 256 + tid) * 8;
            int c = e >> 6, k0 = e & 63;
            const float* src = Bf + (size_t)n * sB + (size_t)(q0 + c) * ldb + kt + k0;
            float4 w0 = *(const float4*)src;
            float4 w1 = *(const float4*)(src + 4);
            float xs[8] = {w0.x, w0.y, w0.z, w0.w, w1.x, w1.y, w1.z, w1.w};
            u16 h[8], l[8];
            #pragma unroll
            for (int q = 0; q < 8; ++q) splitbf(xs[q], h[q], l[q]);
            int b = c * LDK + k0;
            *(bf16x8*)(sBH + b) = (bf16x8){(short)h[0], (short)h[1], (short)h[2], (short)h[3],
                                           (short)h[4], (short)h[5], (short)h[6], (short)h[7]};
            *(bf16x8*)(sBL + b) = (bf16x8){(short)l[0], (short)l[1], (short)l[2], (short)l[3],
                                           (short)l[4], (short)l[5], (short)l[6], (short)l[7]};
        }
        __syncthreads();
        #pragma unroll
        for (int kk = 0; kk < 2; ++kk) {
            int klocal = kk * 32 + (lane >> 4) * 8;
            bf16x8 aH[WM], aL[WM], bH[WN], bL[WN];
            #pragma unroll
            for (int mi = 0; mi < WM; ++mi) {
                int row = (wm * WM + mi) * 16 + (lane & 15);
                aH[mi] = *(const bf16x8*)(sAH + row * LDK + klocal);
                aL[mi] = *(const bf16x8*)(sAL + row * LDK + klocal);
            }
            #pragma unroll
            for (int ni = 0; ni < WN; ++ni) {
                int col = (wn * WN + ni) * 16 + (lane & 15);
                bH[ni] = *(const bf16x8*)(sBH + col * LDK + klocal);
                bL[ni] = *(const bf16x8*)(sBL + col * LDK + klocal);
            }
            #pragma unroll
            for (int mi = 0; mi < WM; ++mi)
                #pragma unroll
                for (int ni = 0; ni < WN; ++ni) {
                    acc[mi][ni] = __builtin_amdgcn_mfma_f32_16x16x32_bf16(aH[mi], bH[ni], acc[mi][ni], 0, 0, 0);
                    acc[mi][ni] = __builtin_amdgcn_mfma_f32_16x16x32_bf16(aH[mi], bL[ni], acc[mi][ni], 0, 0, 0);
                    acc[mi][ni] = __builtin_amdgcn_mfma_f32_16x16x32_bf16(aL[mi], bH[ni], acc[mi][ni], 0, 0, 0);
                }
        }
        __syncthreads();
    }

    #pragma unroll
    for (int mi = 0; mi < WM; ++mi) {
        #pragma unroll
        for (int ni = 0; ni < WN; ++ni) {
            int col = q0 + (wn * WN + ni) * 16 + (lane & 15);
            int rowb = m0 + (wm * WM + mi) * 16 + (lane >> 4) * 4;
            #pragma unroll
            for (int r = 0; r < 4; ++r) {
                int row = rowb + r;
                float val = acc[mi][ni][r];
                if (MODE == 0) {
                    Cf[(size_t)n * sCf + (size_t)col * ldc + row] = val;
                } else if (MODE == 2) {
                    val = fmaxf(val + e1[row], 0.f) + e2[(size_t)n * se2 + (size_t)row * ldc + col];
                    Cf[(size_t)n * sCf + (size_t)row * ldc + col] = val;
                } else if (MODE == 3) {
                    val = 0.5f * val + 0.5f * e2[(size_t)n * se2 + (size_t)row * ldc + col];
                    Cf[(size_t)n * sCf + (size_t)row * ldc + col] = val;
                } else if (MODE == 4) {
                    val = 0.5f * val + 0.5f * e2[(size_t)n * se2 + (size_t)row * HW + col];
                    Cf[(size_t)n * sCf + (size_t)col * ldc + row] = val;
                } else {  // MODE 5: conv + bias
                    val = val + e1[row];
                    Cf[(size_t)n * sCf + (size_t)row * ldc + col] = val;
                }
            }
        }
    }
}

// ---------------- adjacency/reduction chain (verified) ----------------
__global__ void k_dinv(const float* __restrict__ u, const float* __restrict__ vv,
                       const float* __restrict__ dsum,
                       float* __restrict__ dcinv, float* __restrict__ dsinv) {
    int p = blockIdx.x, n = blockIdx.y, tid = threadIdx.x;
    const float* un = u + n * HW;
    const float* vn = vv + n * HW;
    float up = un[p], vp = vn[p];
    float acc_c = 0.f;
    for (int q = tid; q < HW; q += 256) {
        float x = up * vn[q]; x = x < 0.15f ? 0.f : x;
        float y = un[q] * vp; y = y < 0.15f ? 0.f : y;
        acc_c += 0.5f * (x + y);
    }
    __shared__ float s4[4];
    acc_c = blockReduceSum(acc_c, s4);
    if (tid == 0) {
        dcinv[n * HW + p] = 1.0f / sqrtf(acc_c + 1.0f);
        dsinv[n * HW + p] = 1.0f / sqrtf(dsum[n * HW + p] + 1.0f);
    }
}

__global__ void k_build_sim(float* __restrict__ B, const float* __restrict__ u,
                            const float* __restrict__ vv, const float* __restrict__ dcinv,
                            const float* __restrict__ dsinv, float* __restrict__ dfinv) {
    int p = blockIdx.x, n = blockIdx.y, tid = threadIdx.x;
    float* Bb = B + (size_t)n * HW * HW + (size_t)p * HW;
    const float* un = u + n * HW;
    const float* vn = vv + n * HW;
    const float* dci = dcinv + n * HW;
    const float* dsi = dsinv + n * HW;
    float up = un[p], vp = vn[p], dcp = dci[p], dsp = dsi[p];
    float acc = 0.f;
    for (int q = tid; q < HW; q += 256) {
        float x = up * vn[q]; x = x < 0.15f ? 0.f : x;
        float y = un[q] * vp; y = y < 0.15f ? 0.f : y;
        float delta = (q == p) ? 1.0f : 0.0f;
        float val = (0.5f * (x + y) + delta) * dcp * dci[q] + (Bb[q] + delta) * dsp * dsi[q];
        Bb[q] = val;
        acc += val;
    }
    __shared__ float s4[4];
    acc = blockReduceSum(acc, s4);
    if (tid == 0) dfinv[n * HW + p] = 1.0f / sqrtf(acc + 1.0f);
}

__global__ void k_norm_accum(float* __restrict__ B, const float* __restrict__ dfinv,
                             float* __restrict__ ACC, int first) {
    int p = blockIdx.x, n = blockIdx.y, tid = threadIdx.x;
    float* Bb = B + (size_t)n * HW * HW + (size_t)p * HW;
    float* Ab = ACC + (size_t)n * HW * HW + (size_t)p * HW;
    const float* df = dfinv + n * HW;
    float dfp = df[p];
    for (int q = tid; q < HW; q += 256) {
        float val = (Bb[q] + ((q == p) ? 1.f : 0.f)) * dfp * df[q];
        Bb[q] = val;
        Ab[q] = first ? val : (Ab[q] + val);
    }
}

__global__ void k_final_rowsum(const float* __restrict__ ACC, float* __restrict__ dinv) {
    int p = blockIdx.x, n = blockIdx.y, tid = threadIdx.x;
    const float* Ab = ACC + (size_t)n * HW * HW + (size_t)p * HW;
    float acc = 0.f;
    for (int q = tid; q < HW; q += 256) acc += Ab[q];
    __shared__ float s4[4];
    acc = blockReduceSum(acc, s4);
    if (tid == 0) dinv[n * HW + p] = 1.0f / sqrtf(acc * (1.0f / 3.0f) + 1.0f);
}

__global__ void k_final_norm(float* __restrict__ ACC, const float* __restrict__ dinv,
                             float* __restrict__ rowsf, float* __restrict__ diagrow,
                             float* __restrict__ sqrow) {
    int p = blockIdx.x, n = blockIdx.y, tid = threadIdx.x;
    float* Ab = ACC + (size_t)n * HW * HW + (size_t)p * HW;
    const float* di = dinv + n * HW;
    float dp = di[p];
    float accr = 0.f, accsq = 0.f, accd = 0.f;
    for (int q = tid; q < HW; q += 256) {
        float val = (Ab[q] * (1.0f / 3.0f) + ((q == p) ? 1.f : 0.f)) * dp * di[q];
        Ab[q] = val;
        accr += val;
        accsq += val * val;
        if (q == p) accd = val;
    }
    __shared__ float s4[4];
    accr = blockReduceSum(accr, s4);
    accsq = blockReduceSum(accsq, s4);
    accd = blockReduceSum(accd, s4);
    if (tid == 0) {
        rowsf[n * HW + p] = accr;
        sqrow[n * HW + p] = accsq;
        diagrow[n * HW + p] = accd;
    }
}

__global__ void k_scal(const float* __restrict__ diagrow, const float* __restrict__ sqrow,
                       float* __restrict__ scal) {
    int tid = threadIdx.x;
    float a = 0.f, b = 0.f;
    for (int i = tid; i < NB * HW; i += 256) { a += diagrow[i]; b += sqrow[i]; }
    __shared__ float s4[4];
    a = blockReduceSum(a, s4);
    b = blockReduceSum(b, s4);
    if (tid == 0) { scal[0] = a; scal[1] = b; }
}

__global__ void k_reg(const float* __restrict__ rowsf, const float* __restrict__ scal,
                      float* __restrict__ outreg) {
    int n = blockIdx.x, tid = threadIdx.x;
    float acc = 0.f;
    for (int p = tid; p < HW; p += 256) acc += logf(rowsf[n * HW + p]);
    __shared__ float s4[4];
    acc = blockReduceSum(acc, s4);
    if (tid == 0) {
        float f = -0.1f * acc / 1024.0f + 0.1f * sqrtf(scal[1]) / 1048576.0f;
        outreg[n] = 0.1f * scal[0] + f;
    }
}

__global__ void k_appnp_t(const float* __restrict__ ori, const float* __restrict__ wa1,
                          const float* __restrict__ ba1, const float* __restrict__ wa2,
                          const float* __restrict__ ba2, float* __restrict__ T) {
    int p = blockIdx.x, n = blockIdx.y, tid = threadIdx.x;
    const float* x = ori + (size_t)n * C * HW + (size_t)p * C;
    float xv = x[tid];
    __shared__ float s4[4];
    __shared__ float h[3];
    float d0 = blockReduceSum(xv * wa1[0 * C + tid], s4);
    float d1 = blockReduceSum(xv * wa1[1 * C + tid], s4);
    float d2 = blockReduceSum(xv * wa1[2 * C + tid], s4);
    if (tid == 0) {
        h[0] = fmaxf(d0 + ba1[0], 0.f);
        h[1] = fmaxf(d1 + ba1[1], 0.f);
        h[2] = fmaxf(d2 + ba1[2], 0.f);
    }
    __syncthreads();
    float t = h[0] * wa2[tid * 3 + 0] + h[1] * wa2[tid * 3 + 1] + h[2] * wa2[tid * 3 + 2] + ba2[tid];
    T[(size_t)n * HW * C + (size_t)p * C + tid] = fmaxf(t, 0.f);
}

// =====================================================================================
extern "C" void kernel_launch(void* const* d_in, const int* in_sizes, int n_in,
                              void* d_out, int out_size, void* d_ws, size_t ws_size,
                              hipStream_t stream) {
    const float* seg_in = (const float*)d_in[0];
    const float* edge   = (const float*)d_in[1];
    const float* ws1    = (const float*)d_in[2];
    const float* bs1    = (const float*)d_in[3];
    const float* ws11   = (const float*)d_in[4];
    const float* bs11   = (const float*)d_in[5];
    const float* ws2    = (const float*)d_in[6];
    const float* bs2    = (const float*)d_in[7];
    const float* ws3    = (const float*)d_in[8];
    const float* bs3    = (const float*)d_in[9];
    const float* wmlp   = (const float*)d_in[10];
    const float* bmlp   = (const float*)d_in[11];
    const float* wgcn   = (const float*)d_in[12];
    const float* bgcn   = (const float*)d_in[13];
    const float* wa1    = (const float*)d_in[14];
    const float* ba1    = (const float*)d_in[15];
    const float* wa2    = (const float*)d_in[16];
    const float* ba2    = (const float*)d_in[17];

    float* out = (float*)d_out;
    float* w = (float*)d_ws;
    float* SEG_A   = w; w += (size_t)NB * C * HW;        // 8 MB
    float* SEG_SIMT= w; w += (size_t)NB * C * HW;        // 8 MB
    float* SEGSC   = w; w += (size_t)NB * 128 * HW;      // 4 MB  rows 0-63 seg_s, 64-127 seg_c
    float* SEGCT   = w; w += (size_t)NB * NS * HW;       // 2 MB
    float* SEGT    = w; w += (size_t)NB * HW * C;        // 8 MB  seg^T per image
    float* TBUF    = w; w += (size_t)NB * HW * C;        // 8 MB
    float* OBUF    = w; w += (size_t)NB * HW * C;        // 8 MB
    float* BBUF    = w; w += (size_t)NB * HW * HW;       // 32 MB
    float* ACCUM   = w; w += (size_t)NB * HW * HW;       // 32 MB
    float* MAXS    = w; w += (size_t)8 * NB * HW;        // chunked partial maxes
    float* MAXE    = w; w += (size_t)8 * NB * HW;
    float* WCAT    = w; w += (size_t)128 * C;
    float* BCAT    = w; w += 128;
    float* ubuf    = w; w += NB * HW;
    float* vbuf    = w; w += NB * HW;
    float* ssbuf   = w; w += NB * HW;
    float* embuf   = w; w += NB * HW;
    float* dsum    = w; w += NB * HW;
    float* dcinv   = w; w += NB * HW;
    float* dsinv   = w; w += NB * HW;
    float* dfinv   = w; w += NB * HW;
    float* rowsf   = w; w += NB * HW;
    float* diagrow = w; w += NB * HW;
    float* sqrow   = w; w += NB * HW;
    float* pooled  = w; w += NB * C;
    float* cabuf   = w; w += NB * NS;
    float* scal    = w; w += 16;

    const long long sAdj = (long long)HW * HW;
    const long long sSeg = (long long)C * HW;
    const long long sSC  = (long long)128 * HW;

    k_prepw<<<dim3(64), 256, 0, stream>>>(ws1, bs1, ws11, bs11, WCAT, BCAT);

    for (int it = 0; it < 3; ++it) {
        const float* seg_src = (it == 0) ? seg_in : SEG_A;
        // seg^T [HW][C] per image
        k_transp<C, HW><<<dim3(4, 16, NB), 256, 0, stream>>>(seg_src, sSeg, SEGT, sSeg);
        // both 1x1 convs in one MFMA: SEGSC[0:64]=seg_s, [64:128]=seg_c
        k_mfma2<128, 64, 5><<<dim3(16, 1, NB), 256, 0, stream>>>(
            WCAT, 0, C, SEGT, sSeg, C, C,
            SEGSC, sSC, HW, BCAT, nullptr, 0);
        // seg_c^T for bbuild
        k_transp<NS, HW><<<dim3(1, 16, NB), 256, 0, stream>>>(SEGSC + (size_t)64 * HW, sSC, SEGCT, (long long)NS * HW);
        k_pooled<<<dim3(C, NB), 256, 0, stream>>>(seg_src, pooled);
        k_ca<<<dim3(NB), 64, 0, stream>>>(pooled, wmlp, bmlp, cabuf);
        k_maxes<<<dim3(4, NB, 8), 256, 0, stream>>>(seg_src, edge, MAXS, MAXE);
        k_maxfin<<<dim3(4, NB), 256, 0, stream>>>(MAXS, MAXE, ws2, bs2, ws3, bs3, ssbuf, embuf);
        k_uv<<<dim3(4, NB, 2), 256, 0, stream>>>(SEGSC, cabuf, ubuf, vbuf);
        hipMemsetAsync(dsum, 0, (size_t)NB * HW * sizeof(float), stream);
        k_bbuild<<<dim3(136, NB), 256, 0, stream>>>(SEGSC + (size_t)64 * HW, sSC, SEGCT,
                                                    embuf, ssbuf, BBUF, dsum);
        k_dinv<<<dim3(HW, NB), 256, 0, stream>>>(ubuf, vbuf, dsum, dcinv, dsinv);
        k_build_sim<<<dim3(HW, NB), 256, 0, stream>>>(BBUF, ubuf, vbuf, dcinv, dsinv, dfinv);
        k_norm_accum<<<dim3(HW, NB), 256, 0, stream>>>(BBUF, dfinv, ACCUM, it == 0 ? 1 : 0);
        // seg_sim^T = (seg @ sim)^T : NT, Bsrc = sim (symmetric), MODE 0 -> [pos][ch]
        k_mfma2<64, 128, 0><<<dim3(8, 4, NB), 256, 0, stream>>>(
            seg_src, sSeg, HW, BBUF, sAdj, HW, HW,
            SEG_SIMT, sSeg, C, nullptr, nullptr, 0);
        // seg' = relu(wgcn @ seg_sim + bgcn) + seg : NT, Bsrc = SEG_SIMT, MODE 2
        k_mfma2<64, 128, 2><<<dim3(8, 4, NB), 256, 0, stream>>>(
            wgcn, 0, C, SEG_SIMT, sSeg, C, C,
            SEG_A, sSeg, HW, bgcn, seg_src, sSeg);
    }

    // final adjacency + regularizer
    k_final_rowsum<<<dim3(HW, NB), 256, 0, stream>>>(ACCUM, dcinv);
    k_final_norm<<<dim3(HW, NB), 256, 0, stream>>>(ACCUM, dcinv, rowsf, diagrow, sqrow);
    k_scal<<<dim3(1), 256, 0, stream>>>(diagrow, sqrow, scal);
    k_reg<<<dim3(NB), 256, 0, stream>>>(rowsf, scal, out + (size_t)NB * C * HW);

    // APPNP, transposed formulation: Yt = 0.5 * Xt @ adj + 0.5 * Tt  (adj symmetric)
    k_appnp_t<<<dim3(HW, NB), 256, 0, stream>>>(seg_in, wa1, ba1, wa2, ba2, TBUF);
    k_transp<HW, C><<<dim3(16, 4, NB), 256, 0, stream>>>(TBUF, sSeg, SEG_SIMT, sSeg);  // Tt
    k_mfma2<64, 128, 3><<<dim3(8, 4, NB), 256, 0, stream>>>(
        SEG_SIMT, sSeg, HW, ACCUM, sAdj, HW, HW,
        TBUF, sSeg, HW, nullptr, SEG_SIMT, sSeg);
    k_mfma2<64, 128, 3><<<dim3(8, 4, NB), 256, 0, stream>>>(
        TBUF, sSeg, HW, ACCUM, sAdj, HW, HW,
        OBUF, sSeg, HW, nullptr, SEG_SIMT, sSeg);
    k_mfma2<64, 128, 4><<<dim3(8, 4, NB), 256, 0, stream>>>(
        OBUF, sSeg, HW, ACCUM, sAdj, HW, HW,
        out, sSeg, C, nullptr, SEG_SIMT, sSeg);
}